// Round 9
// baseline (204.324 us; speedup 1.0000x reference)
//
#include <hip/hip_runtime.h>
#include <hip/hip_bf16.h>
#include <stdint.h>

#define S_LEN 4096
#define C_DIM 512
#define NGROUPS 32
#define EPS_GN 1e-5f
#define QSCALE 0.044194173824159216f   // 512^-0.5

typedef float f32x4 __attribute__((ext_vector_type(4)));
typedef float f32x16 __attribute__((ext_vector_type(16)));
typedef __bf16 bf16x8 __attribute__((ext_vector_type(8)));
typedef unsigned short u16;
typedef unsigned int u32;

__device__ __forceinline__ u16 f2bf(float f) {
    union { float f; u32 u; } v; v.f = f;
    u32 r = v.u + 0x7FFFu + ((v.u >> 16) & 1u);
    return (u16)(r >> 16);
}
__device__ __forceinline__ u32 pack2(float a, float b) {
    return (u32)f2bf(a) | ((u32)f2bf(b) << 16);
}

// async global->LDS 16B per lane; LDS dest is wave-uniform base + lane*16
__device__ __forceinline__ void async16(const void* g, void* l) {
    __builtin_amdgcn_global_load_lds((const __attribute__((address_space(1))) u32*)g,
                                     (__attribute__((address_space(3))) u32*)l, 16, 0, 0);
}

#define BARRIER() do { asm volatile("" ::: "memory"); __builtin_amdgcn_s_barrier(); asm volatile("" ::: "memory"); } while (0)
#define WAIT_LGKM0() asm volatile("s_waitcnt lgkmcnt(0)" ::: "memory")
#define WAIT_VM0()   asm volatile("s_waitcnt vmcnt(0)" ::: "memory")

// ---------------- fused GroupNorm statistics + weight fp32->bf16 ----------------
// blocks [0,64): gn stats for (b,g); blocks [64,1088): weight conversion chunks
__global__ __launch_bounds__(256) void gn_wconv_kernel(const float* __restrict__ x,
                                                       const float* __restrict__ wq,
                                                       const float* __restrict__ wk,
                                                       const float* __restrict__ wv,
                                                       const float* __restrict__ wo,
                                                       float* __restrict__ stats,
                                                       u16* __restrict__ wb) {
    const int tid = threadIdx.x;
    if (blockIdx.x >= 64) {
        const int i = (blockIdx.x - 64) * 256 + tid;  // 262144 float4 total
        const int m = i >> 16;
        const int j = i & 65535;
        const float* src = (m == 0) ? wq : (m == 1) ? wk : (m == 2) ? wv : wo;
        const float4 v = ((const float4*)src)[j];
        ushort4 o;
        o.x = f2bf(v.x); o.y = f2bf(v.y); o.z = f2bf(v.z); o.w = f2bf(v.w);
        ((ushort4*)wb)[i] = o;
        return;
    }
    const int bg = blockIdx.x;                       // b*32+g, 64 total
    const float* p = x + (size_t)bg * (16 * S_LEN);  // 16 channels * 4096, contiguous
    float s = 0.f, ss = 0.f;
    for (int i = tid; i < (16 * S_LEN) / 4; i += 256) {
        const float4 v = ((const float4*)p)[i];
        s += v.x + v.y + v.z + v.w;
        ss += v.x * v.x + v.y * v.y + v.z * v.z + v.w * v.w;
    }
#pragma unroll
    for (int off = 32; off > 0; off >>= 1) {
        s += __shfl_down(s, off);
        ss += __shfl_down(ss, off);
    }
    __shared__ float rs_[4], rss_[4];
    if ((tid & 63) == 0) { rs_[tid >> 6] = s; rss_[tid >> 6] = ss; }
    __syncthreads();
    if (tid == 0) {
        const float S = rs_[0] + rs_[1] + rs_[2] + rs_[3];
        const float SS = rss_[0] + rss_[1] + rss_[2] + rss_[3];
        const float mean = S * (1.f / 65536.f);
        const float var = SS * (1.f / 65536.f) - mean * mean;
        stats[bg * 2] = mean;
        stats[bg * 2 + 1] = rsqrtf(var + EPS_GN);
    }
}

// ---------------- normalize + transpose to h[b][s][c] bf16 ----------------
__global__ __launch_bounds__(256) void hnorm_kernel(const float* __restrict__ x,
                                                    const float* __restrict__ stats,
                                                    const float* __restrict__ gw,
                                                    const float* __restrict__ gb,
                                                    u16* __restrict__ h) {
    __shared__ float tile[32][65];
    const int b = blockIdx.z, c0 = blockIdx.y * 32, s0 = blockIdx.x * 64;
    const int tid = threadIdx.x;
#pragma unroll
    for (int kq = 0; kq < 2; ++kq) {
        const int f = tid + kq * 256;
        const int c = f >> 4, cs = f & 15;
        const float4 v = *(const float4*)(x + ((size_t)(b * C_DIM + c0 + c) * S_LEN + s0 + cs * 4));
        const int g = (c0 + c) >> 4;
        const float mean = stats[(b * NGROUPS + g) * 2];
        const float rstd = stats[(b * NGROUPS + g) * 2 + 1];
        const float a = rstd * gw[c0 + c];
        const float be = gb[c0 + c] - mean * a;
        tile[c][cs * 4 + 0] = v.x * a + be;
        tile[c][cs * 4 + 1] = v.y * a + be;
        tile[c][cs * 4 + 2] = v.z * a + be;
        tile[c][cs * 4 + 3] = v.w * a + be;
    }
    __syncthreads();
#pragma unroll
    for (int kq = 0; kq < 2; ++kq) {
        const int f = tid + kq * 256;
        const int s = f >> 3, c4 = f & 7;
        ushort4 o;
        o.x = f2bf(tile[c4 * 4 + 0][s]);
        o.y = f2bf(tile[c4 * 4 + 1][s]);
        o.z = f2bf(tile[c4 * 4 + 2][s]);
        o.w = f2bf(tile[c4 * 4 + 3][s]);
        *(ushort4*)(h + ((size_t)(b * S_LEN + s0 + s) * C_DIM + c0 + c4 * 4)) = o;
    }
}

// ---------------- 128x128 GEMM (A[m][k] bf16, W[n][k] bf16), BK=64 ----------------
// MODE 0: QKV projection (nt selects q/k/v); MODE 1: out projection + residual
// Grid: (nt, mt) — nt fastest so consecutive blocks share the A-tile (L2/L3 locality).
template <int MODE>
__global__ __launch_bounds__(256) void proj_kernel(
    const u16* __restrict__ A, const u16* __restrict__ W,
    const float* __restrict__ bias0, const float* __restrict__ bias1,
    const float* __restrict__ bias2,
    u16* __restrict__ oq, u16* __restrict__ ok_, u16* __restrict__ ovT,
    const float* __restrict__ xres, float* __restrict__ out) {
    __shared__ u16 As[128 * 64];
    __shared__ u16 Bs[128 * 64];

    const int mt = blockIdx.y;
    const int nt = blockIdx.x;
    const int m0 = mt * 128;
    const int which = (MODE == 0) ? (nt >> 2) : 0;
    const int n0 = (MODE == 0) ? ((nt & 3) * 128) : (nt * 128);

    const u16* Ab = A + (size_t)m0 * C_DIM;
    const u16* Bb = W + (size_t)which * (C_DIM * C_DIM) + (size_t)n0 * C_DIM;

    const int tid = threadIdx.x;
    const int w = tid >> 6, l = tid & 63, lr = l & 15, lg = l >> 4;
    const int wr = (w >> 1) * 64, wc = (w & 1) * 64;

    f32x4 acc[4][4];
#pragma unroll
    for (int i = 0; i < 4; ++i)
#pragma unroll
        for (int j = 0; j < 4; ++j) acc[i][j] = (f32x4){0.f, 0.f, 0.f, 0.f};

    for (int ks = 0; ks < 8; ++ks) {
        const int k0 = ks * 64;
#pragma unroll
        for (int i = 0; i < 4; ++i) {
            const int ch = w * 4 + i;               // 16 chunks of 8 rows
            const int row = ch * 8 + (l >> 3);
            const int sp = (l & 7) ^ (row & 7);     // source-side swizzle (T2 / G21)
            async16(Ab + (size_t)row * C_DIM + k0 + sp * 8, (void*)(As + ch * 512));
            async16(Bb + (size_t)row * C_DIM + k0 + sp * 8, (void*)(Bs + ch * 512));
        }
        asm volatile("s_waitcnt vmcnt(0)" ::: "memory");
        __syncthreads();
#pragma unroll
        for (int kk = 0; kk < 2; ++kk) {
            bf16x8 af[4], bfr[4];
#pragma unroll
            for (int i = 0; i < 4; ++i) {
                const int row = wr + i * 16 + lr;
                const int p = (kk * 4 + lg) ^ (row & 7);
                af[i] = *(const bf16x8*)(As + row * 64 + p * 8);
            }
#pragma unroll
            for (int j = 0; j < 4; ++j) {
                const int row = wc + j * 16 + lr;
                const int p = (kk * 4 + lg) ^ (row & 7);
                bfr[j] = *(const bf16x8*)(Bs + row * 64 + p * 8);
            }
#pragma unroll
            for (int i = 0; i < 4; ++i)
#pragma unroll
                for (int j = 0; j < 4; ++j)
                    acc[i][j] = __builtin_amdgcn_mfma_f32_16x16x32_bf16(af[i], bfr[j], acc[i][j], 0, 0, 0);
        }
        __syncthreads();
    }

    const float* bias = (MODE == 0) ? (which == 0 ? bias0 : (which == 1 ? bias1 : bias2)) : bias0;
#pragma unroll
    for (int j = 0; j < 4; ++j) {
        const int gc = n0 + wc + j * 16 + lr;
        const float bv = bias[gc];
#pragma unroll
        for (int i = 0; i < 4; ++i) {
            const int gr0 = m0 + wr + i * 16 + lg * 4;
#pragma unroll
            for (int r = 0; r < 4; ++r) {
                const int gr = gr0 + r;
                const float v = acc[i][j][r] + bv;
                if (MODE == 0) {
                    if (which == 0)
                        oq[(size_t)gr * C_DIM + gc] = f2bf(v * QSCALE);
                    else if (which == 1)
                        ok_[(size_t)gr * C_DIM + gc] = f2bf(v);
                    else  // v stored transposed: [b][c][s]
                        ovT[((size_t)(gr >> 12) * C_DIM + gc) * S_LEN + (gr & (S_LEN - 1))] = f2bf(v);
                } else {
                    const size_t idx = ((size_t)(gr >> 12) * C_DIM + gc) * S_LEN + (gr & (S_LEN - 1));
                    out[idx] = v + xres[idx];
                }
            }
        }
    }
}

// ---------------- flash attention: q-tile 128, 8 waves, K+V dbuf, counted vmcnt ----------------
// grid 256 (1 block/CU); 160 KB LDS: K dbuf 2x32K | V dbuf 2x32K | Sx 32K.
// Per step: [issue K(t+1)] QK(t) -> Sx b128 exchange (vmcnt(4): V(t) drained, K flying)
//           [issue V(t+1)] softmax -> cvt_pk pack -> PV(t) -> vmcnt(4): K(t+1) drained, V flying.
__global__ __launch_bounds__(512, 2) void flash_kernel(
    const u16* __restrict__ q, const u16* __restrict__ k, const u16* __restrict__ vT,
    u16* __restrict__ opart, float* __restrict__ ml) {
    __shared__ u16 LDSU[81920];                 // 160 KB exactly
    float* const Sx = (float*)(LDSU + 65536);   // bytes [131072, 163840)

    const int bid = blockIdx.x;
    const int wgid = (bid & 7) * 32 + (bid >> 3);   // XCD swizzle: one (b,sp) per XCD
    const int qt = wgid & 31;
    const int sp = (wgid >> 5) & 3;
    const int b = wgid >> 7;
    const int m0 = qt * 128;
    const int tbeg = sp * 1024;

    const int tid = threadIdx.x;
    const int w = tid >> 6;
    const int l = tid & 63;
    const int rg = w >> 1;            // q row-group (32 rows)
    const int h = w & 1;              // c-half (QK) / d-half (PV)
    const int ln = l & 31;
    const int hi = l >> 5;

    // Q as B-fragments (swapped QK^T), c-half per wave
    bf16x8 qf[16];
    {
        const u16* qrow = q + ((size_t)(b * S_LEN) + m0 + rg * 32 + ln) * C_DIM + h * 256 + hi * 8;
#pragma unroll
        for (int cc = 0; cc < 16; ++cc)
            qf[cc] = *(const bf16x8*)(qrow + cc * 16);
    }

    f32x16 oacc[8];
#pragma unroll
    for (int dt = 0; dt < 8; ++dt)
#pragma unroll
        for (int r = 0; r < 16; ++r) oacc[dt][r] = 0.f;
    float rm = -3.0e38f, rl = 0.f;

    const u16* kbase = k + (size_t)b * S_LEN * C_DIM;
    const u16* vbase = vT + (size_t)b * C_DIM * S_LEN;

    // prologue: stage K(0), V(0) into parity-0 buffers; full drain once
#pragma unroll
    for (int i = 0; i < 4; ++i) {
        const int row = w * 4 + i;
        async16(kbase + (size_t)(tbeg + row) * C_DIM + ((l ^ (row & 7)) * 8),
                (void*)(LDSU + row * 512));
    }
#pragma unroll
    for (int i = 0; i < 4; ++i) {
        const int ch = w * 4 + i;
        const int d0 = ch * 16;
        const int d = d0 + (l >> 2);
        const int g = (l & 3) ^ ((d >> 1) & 3);
        async16(vbase + (size_t)d * S_LEN + tbeg + g * 8, (void*)(LDSU + 32768 + d0 * 32));
    }
    WAIT_VM0();
    BARRIER();

    for (int step = 0; step < 32; ++step) {
        const int t0 = tbeg + step * 32;
        const u16* kcur = LDSU + (step & 1) * 16384;
        const u16* vcur = LDSU + 32768 + (step & 1) * 16384;

        // issue K(t+1) into other parity (4 loads; drained at bottom vmcnt(4))
        if (step < 31) {
            u16* knxt = LDSU + ((step + 1) & 1) * 16384;
#pragma unroll
            for (int i = 0; i < 4; ++i) {
                const int row = w * 4 + i;
                async16(kbase + (size_t)(t0 + 32 + row) * C_DIM + ((l ^ (row & 7)) * 8),
                        (void*)(knxt + row * 512));
            }
        }

        // S^T = K(c-half) * Q^T : 16 MFMA from prefetched K
        f32x16 sa;
#pragma unroll
        for (int r = 0; r < 16; ++r) sa[r] = 0.f;
        __builtin_amdgcn_s_setprio(1);
#pragma unroll
        for (int cc = 0; cc < 16; ++cc) {
            const int g = h * 32 + cc * 2 + hi;
            const bf16x8 af = *(const bf16x8*)(kcur + ln * 512 + ((g ^ (ln & 7)) * 8));
            sa = __builtin_amdgcn_mfma_f32_32x32x16_bf16(af, qf[cc], sa, 0, 0, 0);
        }
        __builtin_amdgcn_s_setprio(0);

        // Sx exchange with partner wave (w^1): [wave][chunk][lane] f32x4, b128 ops
        {
            float* swb = Sx + w * 1024 + l * 4;
#pragma unroll
            for (int c = 0; c < 4; ++c)
                *(f32x4*)(swb + c * 256) = (f32x4){sa[c * 4 + 0], sa[c * 4 + 1], sa[c * 4 + 2], sa[c * 4 + 3]};
            // B1: own Sx writes done (lgkm); V(t) landed for all waves (vmcnt: drain oldest 4 = V(t), K(t+1) stays)
            if (step < 31) { asm volatile("s_waitcnt vmcnt(4) lgkmcnt(0)" ::: "memory"); }
            else           { asm volatile("s_waitcnt vmcnt(0) lgkmcnt(0)" ::: "memory"); }
            BARRIER();
            const float* prb = Sx + (w ^ 1) * 1024 + l * 4;
#pragma unroll
            for (int c = 0; c < 4; ++c) {
                const f32x4 pv = *(const f32x4*)(prb + c * 256);
                sa[c * 4 + 0] += pv[0];
                sa[c * 4 + 1] += pv[1];
                sa[c * 4 + 2] += pv[2];
                sa[c * 4 + 3] += pv[3];
            }
        }

        // issue V(t+1) into other parity (4 loads; in flight across PV + bottom barrier)
        if (step < 31) {
            u16* vnxt = LDSU + 32768 + ((step + 1) & 1) * 16384;
#pragma unroll
            for (int i = 0; i < 4; ++i) {
                const int ch = w * 4 + i;
                const int d0 = ch * 16;
                const int d = d0 + (l >> 2);
                const int g = (l & 3) ^ ((d >> 1) & 3);
                async16(vbase + (size_t)d * S_LEN + t0 + 32 + g * 8, (void*)(vnxt + d0 * 32));
            }
        }

        // online softmax (lane owns one q column; tree reductions)
        float t8[8];
#pragma unroll
        for (int r = 0; r < 8; ++r) t8[r] = fmaxf(sa[r], sa[r + 8]);
#pragma unroll
        for (int r = 0; r < 4; ++r) t8[r] = fmaxf(t8[r], t8[r + 4]);
        float pm = fmaxf(fmaxf(t8[0], t8[1]), fmaxf(t8[2], t8[3]));
        pm = fmaxf(pm, __shfl_xor(pm, 32));
        if (!__all(pm <= rm + 8.f)) {          // T13 defer-max (rarely triggers)
            const float mn = fmaxf(rm, pm);
            const float al = __expf(rm - mn);
            rl *= al;
#pragma unroll
            for (int dt = 0; dt < 8; ++dt)
#pragma unroll
                for (int r = 0; r < 16; ++r) oacc[dt][r] *= al;
            rm = mn;
        }
#pragma unroll
        for (int r = 0; r < 16; ++r) sa[r] = __expf(sa[r] - rm);
        {
            float s8[8];
#pragma unroll
            for (int r = 0; r < 8; ++r) s8[r] = sa[r] + sa[r + 8];
#pragma unroll
            for (int r = 0; r < 4; ++r) s8[r] += s8[r + 4];
            float rs = (s8[0] + s8[1]) + (s8[2] + s8[3]);
            rs += __shfl_xor(rs, 32);
            rl += rs;
        }

        // pack P to bf16 via v_cvt_pk (T12); redistribute across lane halves
        u32 wv[8], pw[8];
#pragma unroll
        for (int s4 = 0; s4 < 4; ++s4) {
            asm("v_cvt_pk_bf16_f32 %0, %1, %2" : "=v"(wv[s4 * 2 + 0]) : "v"(sa[s4 * 4 + 0]), "v"(sa[s4 * 4 + 1]));
            asm("v_cvt_pk_bf16_f32 %0, %1, %2" : "=v"(wv[s4 * 2 + 1]) : "v"(sa[s4 * 4 + 2]), "v"(sa[s4 * 4 + 3]));
        }
#pragma unroll
        for (int j = 0; j < 8; ++j) pw[j] = __shfl_xor((int)wv[j], 32);
        union { u32 u[4]; bf16x8 v; } pb0, pb1;
        pb0.u[0] = hi ? pw[2] : wv[0];
        pb0.u[1] = hi ? pw[3] : wv[1];
        pb0.u[2] = hi ? wv[2] : pw[0];
        pb0.u[3] = hi ? wv[3] : pw[1];
        pb1.u[0] = hi ? pw[6] : wv[4];
        pb1.u[1] = hi ? pw[7] : wv[5];
        pb1.u[2] = hi ? wv[6] : pw[4];
        pb1.u[3] = hi ? wv[7] : pw[5];

        // O^T += V^T * P^T from prefetched V (landed & barrier'd at B1)
        __builtin_amdgcn_s_setprio(1);
#pragma unroll
        for (int dt = 0; dt < 8; ++dt) {
            const int d = h * 256 + dt * 32 + ln;
#pragma unroll
            for (int kk = 0; kk < 2; ++kk) {
                const int slot = (kk * 2 + hi) ^ ((d >> 1) & 3);
                const bf16x8 vf = *(const bf16x8*)(vcur + d * 32 + slot * 8);
                oacc[dt] = __builtin_amdgcn_mfma_f32_32x32x16_bf16(vf, kk ? pb1.v : pb0.v, oacc[dt], 0, 0, 0);
            }
        }
        __builtin_amdgcn_s_setprio(0);

        // bottom: own LDS reads done; K(t+1) landed (drain oldest 4, V(t+1) keeps flying)
        asm volatile("s_waitcnt vmcnt(4) lgkmcnt(0)" ::: "memory");
        BARRIER();
    }

    // epilogue: normalize, transpose via LDS (reuse K+V region), coalesced store
    const float inv = 1.f / rl;
    u16* const Ot = LDSU;  // [128 q][512 d] bf16, 16B-granule XOR swizzle by (q&7)
    {
        const int qq = rg * 32 + ln;
#pragma unroll
        for (int dt = 0; dt < 8; ++dt) {
#pragma unroll
            for (int u = 0; u < 8; ++u) {
                const int d = h * 256 + dt * 32 + (((2 * u) & 3) + 8 * (u >> 1) + 4 * hi);
                const u32 word = pack2(oacc[dt][2 * u] * inv, oacc[dt][2 * u + 1] * inv);
                const int byte = qq * 1024 + ((d * 2) ^ ((qq & 7) << 4));
                *(u32*)((char*)Ot + byte) = word;
            }
        }
    }
    if (h == 0 && hi == 0) {
        float* mlp = ml + (size_t)((b * 4 + sp) * 2) * S_LEN;
        mlp[m0 + rg * 32 + ln] = rm;
        mlp[S_LEN + m0 + rg * 32 + ln] = rl;
    }
    WAIT_LGKM0();
    BARRIER();
    {
        u16* od = opart + ((size_t)((b * 4 + sp) * S_LEN) + m0) * C_DIM;
#pragma unroll
        for (int i = 0; i < 16; ++i) {
            const int qq = w * 16 + i;
            const int byte = qq * 1024 + ((l * 16) ^ ((qq & 7) << 4));
            const uint4 tv = *(const uint4*)((char*)Ot + byte);
            *(uint4*)(od + (size_t)qq * C_DIM + l * 8) = tv;
        }
    }
}

// ---------------- merge the four KV-split partials (normalized bf16 + m,l) ----------------
__global__ __launch_bounds__(256) void merge_kernel(const u16* __restrict__ opart,
                                                    const float* __restrict__ ml,
                                                    u16* __restrict__ o) {
    const int row = blockIdx.x;  // b*4096 + s
    const int b = row >> 12, s = row & 4095;
    float mi[4], li[4];
#pragma unroll
    for (int i = 0; i < 4; ++i) {
        const float* mlp = ml + (size_t)((b * 4 + i) * 2) * S_LEN;
        mi[i] = mlp[s];
        li[i] = mlp[S_LEN + s];
    }
    float mm = fmaxf(fmaxf(mi[0], mi[1]), fmaxf(mi[2], mi[3]));
    float wsum = 0.f, wi[4];
#pragma unroll
    for (int i = 0; i < 4; ++i) { wi[i] = __expf(mi[i] - mm) * li[i]; wsum += wi[i]; }
    const float invw = 1.f / wsum;
#pragma unroll
    for (int i = 0; i < 4; ++i) wi[i] *= invw;

    const int c = threadIdx.x * 2;
    float a0 = 0.f, a1 = 0.f;
#pragma unroll
    for (int i = 0; i < 4; ++i) {
        const u16* p = opart + ((size_t)((b * 4 + i) * S_LEN) + s) * C_DIM + c;
        const ushort2 uu = *(const ushort2*)p;
        union { u32 u; float f; } c0, c1;
        c0.u = (u32)uu.x << 16; c1.u = (u32)uu.y << 16;
        a0 += wi[i] * c0.f;
        a1 += wi[i] * c1.f;
    }
    u16* orow = o + (size_t)row * C_DIM;
    ushort2 ov;
    ov.x = f2bf(a0); ov.y = f2bf(a1);
    *(ushort2*)(orow + c) = ov;
}

__global__ void sentinel_kernel(float* out) {
    if (threadIdx.x == 0 && blockIdx.x == 0) out[0] = 12345.0f;
}

extern "C" void kernel_launch(void* const* d_in, const int* in_sizes, int n_in,
                              void* d_out, int out_size, void* d_ws, size_t ws_size,
                              hipStream_t stream) {
    (void)in_sizes; (void)n_in; (void)out_size;
    const float* x  = (const float*)d_in[0];
    const float* gw = (const float*)d_in[1];
    const float* gb = (const float*)d_in[2];
    const float* wq = (const float*)d_in[3];
    const float* bq = (const float*)d_in[4];
    const float* wk = (const float*)d_in[5];
    const float* bk = (const float*)d_in[6];
    const float* wv = (const float*)d_in[7];
    const float* bv = (const float*)d_in[8];
    const float* wo = (const float*)d_in[9];
    const float* bo = (const float*)d_in[10];
    float* out = (float*)d_out;

    // ws layout (bytes):
    // stats 1K | wb 2M | h(=ob) 8M | q 8M | k 8M | vT 8M | opart(bf16) 32M | ml 256K
    const size_t REQ = 69469184;
    if (ws_size < REQ) {
        sentinel_kernel<<<1, 64, 0, stream>>>(out);
        return;
    }
    char* ws = (char*)d_ws;
    float* stats = (float*)ws;
    u16* wb  = (u16*)(ws + 1024);
    u16* h   = (u16*)(ws + 1024 + 2097152);
    u16* qb  = h + (size_t)8192 * 512;
    u16* kb  = qb + (size_t)8192 * 512;
    u16* vTb = kb + (size_t)8192 * 512;
    u16* opart = vTb + (size_t)8192 * 512;            // 2*4*4096*512 bf16 = 32MB
    float* ml = (float*)((char*)opart + (size_t)33554432);
    u16* ob = h;                                      // reuse h after proj0

    gn_wconv_kernel<<<1088, 256, 0, stream>>>(x, wq, wk, wv, wo, stats, wb);
    hnorm_kernel<<<dim3(64, 16, 2), 256, 0, stream>>>(x, stats, gw, gb, h);
    proj_kernel<0><<<dim3(12, 64), 256, 0, stream>>>(h, wb, bq, bk, bv, qb, kb, vTb,
                                                     nullptr, nullptr);
    flash_kernel<<<256, 512, 0, stream>>>(qb, kb, vTb, opart, ml);
    merge_kernel<<<8192, 256, 0, stream>>>(opart, ml, ob);
    proj_kernel<1><<<dim3(4, 64), 256, 0, stream>>>(ob, wb + (size_t)3 * 262144, bo, nullptr,
                                                    nullptr, nullptr, nullptr, nullptr, x, out);
}

// Round 10
// 191.375 us; speedup vs baseline: 1.0677x; 1.0677x over previous
//
#include <hip/hip_runtime.h>
#include <hip/hip_bf16.h>
#include <stdint.h>

#define S_LEN 4096
#define C_DIM 512
#define NGROUPS 32
#define EPS_GN 1e-5f
#define QSCALE 0.044194173824159216f   // 512^-0.5

typedef float f32x4 __attribute__((ext_vector_type(4)));
typedef float f32x16 __attribute__((ext_vector_type(16)));
typedef __bf16 bf16x8 __attribute__((ext_vector_type(8)));
typedef unsigned short u16;
typedef unsigned int u32;

__device__ __forceinline__ u16 f2bf(float f) {
    union { float f; u32 u; } v; v.f = f;
    u32 r = v.u + 0x7FFFu + ((v.u >> 16) & 1u);
    return (u16)(r >> 16);
}
__device__ __forceinline__ u32 pack2(float a, float b) {
    return (u32)f2bf(a) | ((u32)f2bf(b) << 16);
}

// async global->LDS 16B per lane; LDS dest is wave-uniform base + lane*16
__device__ __forceinline__ void async16(const void* g, void* l) {
    __builtin_amdgcn_global_load_lds((const __attribute__((address_space(1))) u32*)g,
                                     (__attribute__((address_space(3))) u32*)l, 16, 0, 0);
}

#define BARRIER() do { asm volatile("" ::: "memory"); __builtin_amdgcn_s_barrier(); asm volatile("" ::: "memory"); } while (0)
#define WAIT_LGKM0() asm volatile("s_waitcnt lgkmcnt(0)" ::: "memory")
#define WAIT_VM0()   asm volatile("s_waitcnt vmcnt(0)" ::: "memory")

// ---------------- fused GroupNorm statistics + weight fp32->bf16 ----------------
// blocks [0,64): gn stats for (b,g); blocks [64,1088): weight conversion chunks
__global__ __launch_bounds__(256) void gn_wconv_kernel(const float* __restrict__ x,
                                                       const float* __restrict__ wq,
                                                       const float* __restrict__ wk,
                                                       const float* __restrict__ wv,
                                                       const float* __restrict__ wo,
                                                       float* __restrict__ stats,
                                                       u16* __restrict__ wb) {
    const int tid = threadIdx.x;
    if (blockIdx.x >= 64) {
        const int i = (blockIdx.x - 64) * 256 + tid;  // 262144 float4 total
        const int m = i >> 16;
        const int j = i & 65535;
        const float* src = (m == 0) ? wq : (m == 1) ? wk : (m == 2) ? wv : wo;
        const float4 v = ((const float4*)src)[j];
        ushort4 o;
        o.x = f2bf(v.x); o.y = f2bf(v.y); o.z = f2bf(v.z); o.w = f2bf(v.w);
        ((ushort4*)wb)[i] = o;
        return;
    }
    const int bg = blockIdx.x;                       // b*32+g, 64 total
    const float* p = x + (size_t)bg * (16 * S_LEN);  // 16 channels * 4096, contiguous
    float s = 0.f, ss = 0.f;
    for (int i = tid; i < (16 * S_LEN) / 4; i += 256) {
        const float4 v = ((const float4*)p)[i];
        s += v.x + v.y + v.z + v.w;
        ss += v.x * v.x + v.y * v.y + v.z * v.z + v.w * v.w;
    }
#pragma unroll
    for (int off = 32; off > 0; off >>= 1) {
        s += __shfl_down(s, off);
        ss += __shfl_down(ss, off);
    }
    __shared__ float rs_[4], rss_[4];
    if ((tid & 63) == 0) { rs_[tid >> 6] = s; rss_[tid >> 6] = ss; }
    __syncthreads();
    if (tid == 0) {
        const float S = rs_[0] + rs_[1] + rs_[2] + rs_[3];
        const float SS = rss_[0] + rss_[1] + rss_[2] + rss_[3];
        const float mean = S * (1.f / 65536.f);
        const float var = SS * (1.f / 65536.f) - mean * mean;
        stats[bg * 2] = mean;
        stats[bg * 2 + 1] = rsqrtf(var + EPS_GN);
    }
}

// ---------------- normalize + transpose to h[b][s][c] bf16 ----------------
__global__ __launch_bounds__(256) void hnorm_kernel(const float* __restrict__ x,
                                                    const float* __restrict__ stats,
                                                    const float* __restrict__ gw,
                                                    const float* __restrict__ gb,
                                                    u16* __restrict__ h) {
    __shared__ float tile[32][65];
    const int b = blockIdx.z, c0 = blockIdx.y * 32, s0 = blockIdx.x * 64;
    const int tid = threadIdx.x;
#pragma unroll
    for (int kq = 0; kq < 2; ++kq) {
        const int f = tid + kq * 256;
        const int c = f >> 4, cs = f & 15;
        const float4 v = *(const float4*)(x + ((size_t)(b * C_DIM + c0 + c) * S_LEN + s0 + cs * 4));
        const int g = (c0 + c) >> 4;
        const float mean = stats[(b * NGROUPS + g) * 2];
        const float rstd = stats[(b * NGROUPS + g) * 2 + 1];
        const float a = rstd * gw[c0 + c];
        const float be = gb[c0 + c] - mean * a;
        tile[c][cs * 4 + 0] = v.x * a + be;
        tile[c][cs * 4 + 1] = v.y * a + be;
        tile[c][cs * 4 + 2] = v.z * a + be;
        tile[c][cs * 4 + 3] = v.w * a + be;
    }
    __syncthreads();
#pragma unroll
    for (int kq = 0; kq < 2; ++kq) {
        const int f = tid + kq * 256;
        const int s = f >> 3, c4 = f & 7;
        ushort4 o;
        o.x = f2bf(tile[c4 * 4 + 0][s]);
        o.y = f2bf(tile[c4 * 4 + 1][s]);
        o.z = f2bf(tile[c4 * 4 + 2][s]);
        o.w = f2bf(tile[c4 * 4 + 3][s]);
        *(ushort4*)(h + ((size_t)(b * S_LEN + s0 + s) * C_DIM + c0 + c4 * 4)) = o;
    }
}

// ---------------- 128x128 GEMM (A[m][k] bf16, W[n][k] bf16), BK=64 ----------------
// MODE 0: QKV projection (nt selects q/k/v); MODE 1: out projection + residual.
// Epilogue goes through LDS (reusing staging space) for fully-coalesced global stores.
template <int MODE>
__global__ __launch_bounds__(256) void proj_kernel(
    const u16* __restrict__ A, const u16* __restrict__ W,
    const float* __restrict__ bias0, const float* __restrict__ bias1,
    const float* __restrict__ bias2,
    u16* __restrict__ oq, u16* __restrict__ ok_, u16* __restrict__ ovT,
    const float* __restrict__ xres, float* __restrict__ out) {
    __shared__ u16 SMEM[128 * 64 * 2];          // 32 KB: As | Bs, reused by epilogue
    u16* const As = SMEM;
    u16* const Bs = SMEM + 8192;

    const int mt = blockIdx.x;
    const int nt = blockIdx.y;
    const int m0 = mt * 128;
    const int which = (MODE == 0) ? (nt >> 2) : 0;
    const int n0 = (MODE == 0) ? ((nt & 3) * 128) : (nt * 128);

    const u16* Ab = A + (size_t)m0 * C_DIM;
    const u16* Bb = W + (size_t)which * (C_DIM * C_DIM) + (size_t)n0 * C_DIM;

    const int tid = threadIdx.x;
    const int w = tid >> 6, l = tid & 63, lr = l & 15, lg = l >> 4;
    const int wr = (w >> 1) * 64, wc = (w & 1) * 64;

    f32x4 acc[4][4];
#pragma unroll
    for (int i = 0; i < 4; ++i)
#pragma unroll
        for (int j = 0; j < 4; ++j) acc[i][j] = (f32x4){0.f, 0.f, 0.f, 0.f};

    for (int ks = 0; ks < 8; ++ks) {
        const int k0 = ks * 64;
#pragma unroll
        for (int i = 0; i < 4; ++i) {
            const int ch = w * 4 + i;               // 16 chunks of 8 rows
            const int row = ch * 8 + (l >> 3);
            const int sp = (l & 7) ^ (row & 7);     // source-side swizzle (T2 / G21)
            async16(Ab + (size_t)row * C_DIM + k0 + sp * 8, (void*)(As + ch * 512));
            async16(Bb + (size_t)row * C_DIM + k0 + sp * 8, (void*)(Bs + ch * 512));
        }
        asm volatile("s_waitcnt vmcnt(0)" ::: "memory");
        __syncthreads();
#pragma unroll
        for (int kk = 0; kk < 2; ++kk) {
            bf16x8 af[4], bfr[4];
#pragma unroll
            for (int i = 0; i < 4; ++i) {
                const int row = wr + i * 16 + lr;
                const int p = (kk * 4 + lg) ^ (row & 7);
                af[i] = *(const bf16x8*)(As + row * 64 + p * 8);
            }
#pragma unroll
            for (int j = 0; j < 4; ++j) {
                const int row = wc + j * 16 + lr;
                const int p = (kk * 4 + lg) ^ (row & 7);
                bfr[j] = *(const bf16x8*)(Bs + row * 64 + p * 8);
            }
#pragma unroll
            for (int i = 0; i < 4; ++i)
#pragma unroll
                for (int j = 0; j < 4; ++j)
                    acc[i][j] = __builtin_amdgcn_mfma_f32_16x16x32_bf16(af[i], bfr[j], acc[i][j], 0, 0, 0);
        }
        __syncthreads();
    }

    if (MODE == 0) {
        const float* bias = (which == 0) ? bias0 : (which == 1 ? bias1 : bias2);
        u16* const Ct = SMEM;                      // 128x128 bf16 = 32 KB
#pragma unroll
        for (int j = 0; j < 4; ++j) {
            const int gcl = wc + j * 16 + lr;
            const float bv = bias[n0 + gcl];
#pragma unroll
            for (int i = 0; i < 4; ++i) {
#pragma unroll
                for (int r = 0; r < 4; ++r) {
                    const int grl = wr + i * 16 + lg * 4 + r;
                    float v = acc[i][j][r] + bv;
                    if (which == 0) v *= QSCALE;
                    const u16 hv = f2bf(v);
                    if (which < 2)
                        Ct[grl * 128 + gcl] = hv;                      // row-major
                    else                                               // transposed + XOR swizzle
                        *(u16*)((char*)Ct + gcl * 256 + ((grl * 2) ^ ((gcl & 7) << 4))) = hv;
                }
            }
        }
        __syncthreads();
        if (which < 2) {
            u16* const dst = (which == 0) ? oq : ok_;
#pragma unroll
            for (int it = 0; it < 8; ++it) {
                const int e = it * 256 + tid;
                const int row = e >> 4, c8 = e & 15;
                const uint4 val = *(const uint4*)(Ct + row * 128 + c8 * 8);
                *(uint4*)(dst + (size_t)(m0 + row) * C_DIM + n0 + c8 * 8) = val;
            }
        } else {
            const int b0 = m0 >> 12, s0 = m0 & (S_LEN - 1);
#pragma unroll
            for (int it = 0; it < 8; ++it) {
                const int e = it * 256 + tid;
                const int crow = e >> 4, c8 = e & 15;
                const uint4 val = *(const uint4*)((char*)Ct + crow * 256 + ((c8 * 16) ^ ((crow & 7) << 4)));
                *(uint4*)(ovT + ((size_t)(b0 * C_DIM + n0 + crow)) * S_LEN + s0 + c8 * 8) = val;
            }
        }
    } else {
        // MODE 1: transposed f32 + residual, two 64-channel passes through 32 KB LDS
        float* const Ctf = (float*)SMEM;           // [64 ch][128 s] f32, XOR-swizzled
        const int b0 = m0 >> 12, s0 = m0 & (S_LEN - 1);
#pragma unroll
        for (int pass = 0; pass < 2; ++pass) {
            if ((w & 1) == pass) {
#pragma unroll
                for (int j = 0; j < 4; ++j) {
                    const int gcl = j * 16 + lr;   // 0..63 within this half
                    const float bv = bias0[n0 + pass * 64 + gcl];
#pragma unroll
                    for (int i = 0; i < 4; ++i) {
#pragma unroll
                        for (int r = 0; r < 4; ++r) {
                            const int grl = wr + i * 16 + lg * 4 + r;
                            const float v = acc[i][j][r] + bv;
                            *(float*)((char*)Ctf + gcl * 512 + ((grl * 4) ^ ((gcl & 7) << 4))) = v;
                        }
                    }
                }
            }
            __syncthreads();
#pragma unroll
            for (int it = 0; it < 8; ++it) {
                const int e = it * 256 + tid;
                const int crow = e >> 5, sg = e & 31;
                const f32x4 cv = *(const f32x4*)((char*)Ctf + crow * 512 + ((sg * 16) ^ ((crow & 7) << 4)));
                const size_t gidx = ((size_t)(b0 * C_DIM + n0 + pass * 64 + crow)) * S_LEN + s0 + sg * 4;
                const f32x4 xr = *(const f32x4*)(xres + gidx);
                *(f32x4*)(out + gidx) = cv + xr;
            }
            __syncthreads();
        }
    }
}

// ---------------- flash attention: q-tile 128, 8 waves, K+V dbuf, counted vmcnt ----------------
// grid 256 (1 block/CU); 160 KB LDS: K dbuf 2x32K | V dbuf 2x32K | Sx 32K.
// Per step: [issue K(t+1)] QK(t) -> Sx b128 exchange (vmcnt(4): V(t) drained, K flying)
//           [issue V(t+1)] softmax -> cvt_pk pack -> PV(t) -> vmcnt(4): K(t+1) drained, V flying.
__global__ __launch_bounds__(512, 2) void flash_kernel(
    const u16* __restrict__ q, const u16* __restrict__ k, const u16* __restrict__ vT,
    u16* __restrict__ opart, float* __restrict__ ml) {
    __shared__ u16 LDSU[81920];                 // 160 KB exactly
    float* const Sx = (float*)(LDSU + 65536);   // bytes [131072, 163840)

    const int bid = blockIdx.x;
    const int wgid = (bid & 7) * 32 + (bid >> 3);   // XCD swizzle: one (b,sp) per XCD
    const int qt = wgid & 31;
    const int sp = (wgid >> 5) & 3;
    const int b = wgid >> 7;
    const int m0 = qt * 128;
    const int tbeg = sp * 1024;

    const int tid = threadIdx.x;
    const int w = tid >> 6;
    const int l = tid & 63;
    const int rg = w >> 1;            // q row-group (32 rows)
    const int h = w & 1;              // c-half (QK) / d-half (PV)
    const int ln = l & 31;
    const int hi = l >> 5;

    // Q as B-fragments (swapped QK^T), c-half per wave
    bf16x8 qf[16];
    {
        const u16* qrow = q + ((size_t)(b * S_LEN) + m0 + rg * 32 + ln) * C_DIM + h * 256 + hi * 8;
#pragma unroll
        for (int cc = 0; cc < 16; ++cc)
            qf[cc] = *(const bf16x8*)(qrow + cc * 16);
    }

    f32x16 oacc[8];
#pragma unroll
    for (int dt = 0; dt < 8; ++dt)
#pragma unroll
        for (int r = 0; r < 16; ++r) oacc[dt][r] = 0.f;
    float rm = -3.0e38f, rl = 0.f;

    const u16* kbase = k + (size_t)b * S_LEN * C_DIM;
    const u16* vbase = vT + (size_t)b * C_DIM * S_LEN;

    // prologue: stage K(0), V(0) into parity-0 buffers; full drain once
#pragma unroll
    for (int i = 0; i < 4; ++i) {
        const int row = w * 4 + i;
        async16(kbase + (size_t)(tbeg + row) * C_DIM + ((l ^ (row & 7)) * 8),
                (void*)(LDSU + row * 512));
    }
#pragma unroll
    for (int i = 0; i < 4; ++i) {
        const int ch = w * 4 + i;
        const int d0 = ch * 16;
        const int d = d0 + (l >> 2);
        const int g = (l & 3) ^ ((d >> 1) & 3);
        async16(vbase + (size_t)d * S_LEN + tbeg + g * 8, (void*)(LDSU + 32768 + d0 * 32));
    }
    WAIT_VM0();
    BARRIER();

    for (int step = 0; step < 32; ++step) {
        const int t0 = tbeg + step * 32;
        const u16* kcur = LDSU + (step & 1) * 16384;
        const u16* vcur = LDSU + 32768 + (step & 1) * 16384;

        // issue K(t+1) into other parity (4 loads; drained at bottom vmcnt(4))
        if (step < 31) {
            u16* knxt = LDSU + ((step + 1) & 1) * 16384;
#pragma unroll
            for (int i = 0; i < 4; ++i) {
                const int row = w * 4 + i;
                async16(kbase + (size_t)(t0 + 32 + row) * C_DIM + ((l ^ (row & 7)) * 8),
                        (void*)(knxt + row * 512));
            }
        }

        // S^T = K(c-half) * Q^T : 16 MFMA from prefetched K
        f32x16 sa;
#pragma unroll
        for (int r = 0; r < 16; ++r) sa[r] = 0.f;
        __builtin_amdgcn_s_setprio(1);
#pragma unroll
        for (int cc = 0; cc < 16; ++cc) {
            const int g = h * 32 + cc * 2 + hi;
            const bf16x8 af = *(const bf16x8*)(kcur + ln * 512 + ((g ^ (ln & 7)) * 8));
            sa = __builtin_amdgcn_mfma_f32_32x32x16_bf16(af, qf[cc], sa, 0, 0, 0);
        }
        __builtin_amdgcn_s_setprio(0);

        // Sx exchange with partner wave (w^1): [wave][chunk][lane] f32x4, b128 ops
        {
            float* swb = Sx + w * 1024 + l * 4;
#pragma unroll
            for (int c = 0; c < 4; ++c)
                *(f32x4*)(swb + c * 256) = (f32x4){sa[c * 4 + 0], sa[c * 4 + 1], sa[c * 4 + 2], sa[c * 4 + 3]};
            // B1: own Sx writes done (lgkm); V(t) landed for all waves (vmcnt: drain oldest 4 = V(t), K(t+1) stays)
            if (step < 31) { asm volatile("s_waitcnt vmcnt(4) lgkmcnt(0)" ::: "memory"); }
            else           { asm volatile("s_waitcnt vmcnt(0) lgkmcnt(0)" ::: "memory"); }
            BARRIER();
            const float* prb = Sx + (w ^ 1) * 1024 + l * 4;
#pragma unroll
            for (int c = 0; c < 4; ++c) {
                const f32x4 pv = *(const f32x4*)(prb + c * 256);
                sa[c * 4 + 0] += pv[0];
                sa[c * 4 + 1] += pv[1];
                sa[c * 4 + 2] += pv[2];
                sa[c * 4 + 3] += pv[3];
            }
        }

        // issue V(t+1) into other parity (4 loads; in flight across PV + bottom barrier)
        if (step < 31) {
            u16* vnxt = LDSU + 32768 + ((step + 1) & 1) * 16384;
#pragma unroll
            for (int i = 0; i < 4; ++i) {
                const int ch = w * 4 + i;
                const int d0 = ch * 16;
                const int d = d0 + (l >> 2);
                const int g = (l & 3) ^ ((d >> 1) & 3);
                async16(vbase + (size_t)d * S_LEN + t0 + 32 + g * 8, (void*)(vnxt + d0 * 32));
            }
        }

        // online softmax (lane owns one q column; tree reductions)
        float t8[8];
#pragma unroll
        for (int r = 0; r < 8; ++r) t8[r] = fmaxf(sa[r], sa[r + 8]);
#pragma unroll
        for (int r = 0; r < 4; ++r) t8[r] = fmaxf(t8[r], t8[r + 4]);
        float pm = fmaxf(fmaxf(t8[0], t8[1]), fmaxf(t8[2], t8[3]));
        pm = fmaxf(pm, __shfl_xor(pm, 32));
        if (!__all(pm <= rm + 8.f)) {          // T13 defer-max (rarely triggers)
            const float mn = fmaxf(rm, pm);
            const float al = __expf(rm - mn);
            rl *= al;
#pragma unroll
            for (int dt = 0; dt < 8; ++dt)
#pragma unroll
                for (int r = 0; r < 16; ++r) oacc[dt][r] *= al;
            rm = mn;
        }
#pragma unroll
        for (int r = 0; r < 16; ++r) sa[r] = __expf(sa[r] - rm);
        {
            float s8[8];
#pragma unroll
            for (int r = 0; r < 8; ++r) s8[r] = sa[r] + sa[r + 8];
#pragma unroll
            for (int r = 0; r < 4; ++r) s8[r] += s8[r + 4];
            float rs = (s8[0] + s8[1]) + (s8[2] + s8[3]);
            rs += __shfl_xor(rs, 32);
            rl += rs;
        }

        // pack P to bf16 via v_cvt_pk (T12); redistribute across lane halves
        u32 wv[8], pw[8];
#pragma unroll
        for (int s4 = 0; s4 < 4; ++s4) {
            asm("v_cvt_pk_bf16_f32 %0, %1, %2" : "=v"(wv[s4 * 2 + 0]) : "v"(sa[s4 * 4 + 0]), "v"(sa[s4 * 4 + 1]));
            asm("v_cvt_pk_bf16_f32 %0, %1, %2" : "=v"(wv[s4 * 2 + 1]) : "v"(sa[s4 * 4 + 2]), "v"(sa[s4 * 4 + 3]));
        }
#pragma unroll
        for (int j = 0; j < 8; ++j) pw[j] = __shfl_xor((int)wv[j], 32);
        union { u32 u[4]; bf16x8 v; } pb0, pb1;
        pb0.u[0] = hi ? pw[2] : wv[0];
        pb0.u[1] = hi ? pw[3] : wv[1];
        pb0.u[2] = hi ? wv[2] : pw[0];
        pb0.u[3] = hi ? wv[3] : pw[1];
        pb1.u[0] = hi ? pw[6] : wv[4];
        pb1.u[1] = hi ? pw[7] : wv[5];
        pb1.u[2] = hi ? wv[6] : pw[4];
        pb1.u[3] = hi ? wv[7] : pw[5];

        // O^T += V^T * P^T from prefetched V (landed & barrier'd at B1)
        __builtin_amdgcn_s_setprio(1);
#pragma unroll
        for (int dt = 0; dt < 8; ++dt) {
            const int d = h * 256 + dt * 32 + ln;
#pragma unroll
            for (int kk = 0; kk < 2; ++kk) {
                const int slot = (kk * 2 + hi) ^ ((d >> 1) & 3);
                const bf16x8 vf = *(const bf16x8*)(vcur + d * 32 + slot * 8);
                oacc[dt] = __builtin_amdgcn_mfma_f32_32x32x16_bf16(vf, kk ? pb1.v : pb0.v, oacc[dt], 0, 0, 0);
            }
        }
        __builtin_amdgcn_s_setprio(0);

        // bottom: own LDS reads done; K(t+1) landed (drain oldest 4, V(t+1) keeps flying)
        asm volatile("s_waitcnt vmcnt(4) lgkmcnt(0)" ::: "memory");
        BARRIER();
    }

    // epilogue: normalize, transpose via LDS (reuse K+V region), coalesced store
    const float inv = 1.f / rl;
    u16* const Ot = LDSU;  // [128 q][512 d] bf16, 16B-granule XOR swizzle by (q&7)
    {
        const int qq = rg * 32 + ln;
#pragma unroll
        for (int dt = 0; dt < 8; ++dt) {
#pragma unroll
            for (int u = 0; u < 8; ++u) {
                const int d = h * 256 + dt * 32 + (((2 * u) & 3) + 8 * (u >> 1) + 4 * hi);
                const u32 word = pack2(oacc[dt][2 * u] * inv, oacc[dt][2 * u + 1] * inv);
                const int byte = qq * 1024 + ((d * 2) ^ ((qq & 7) << 4));
                *(u32*)((char*)Ot + byte) = word;
            }
        }
    }
    if (h == 0 && hi == 0) {
        float* mlp = ml + (size_t)((b * 4 + sp) * 2) * S_LEN;
        mlp[m0 + rg * 32 + ln] = rm;
        mlp[S_LEN + m0 + rg * 32 + ln] = rl;
    }
    WAIT_LGKM0();
    BARRIER();
    {
        u16* od = opart + ((size_t)((b * 4 + sp) * S_LEN) + m0) * C_DIM;
#pragma unroll
        for (int i = 0; i < 16; ++i) {
            const int qq = w * 16 + i;
            const int byte = qq * 1024 + ((l * 16) ^ ((qq & 7) << 4));
            const uint4 tv = *(const uint4*)((char*)Ot + byte);
            *(uint4*)(od + (size_t)qq * C_DIM + l * 8) = tv;
        }
    }
}

// ---------------- merge the four KV-split partials (normalized bf16 + m,l) ----------------
__global__ __launch_bounds__(256) void merge_kernel(const u16* __restrict__ opart,
                                                    const float* __restrict__ ml,
                                                    u16* __restrict__ o) {
    const int row = blockIdx.x;  // b*4096 + s
    const int b = row >> 12, s = row & 4095;
    float mi[4], li[4];
#pragma unroll
    for (int i = 0; i < 4; ++i) {
        const float* mlp = ml + (size_t)((b * 4 + i) * 2) * S_LEN;
        mi[i] = mlp[s];
        li[i] = mlp[S_LEN + s];
    }
    float mm = fmaxf(fmaxf(mi[0], mi[1]), fmaxf(mi[2], mi[3]));
    float wsum = 0.f, wi[4];
#pragma unroll
    for (int i = 0; i < 4; ++i) { wi[i] = __expf(mi[i] - mm) * li[i]; wsum += wi[i]; }
    const float invw = 1.f / wsum;
#pragma unroll
    for (int i = 0; i < 4; ++i) wi[i] *= invw;

    const int c = threadIdx.x * 2;
    float a0 = 0.f, a1 = 0.f;
#pragma unroll
    for (int i = 0; i < 4; ++i) {
        const u16* p = opart + ((size_t)((b * 4 + i) * S_LEN) + s) * C_DIM + c;
        const ushort2 uu = *(const ushort2*)p;
        union { u32 u; float f; } c0, c1;
        c0.u = (u32)uu.x << 16; c1.u = (u32)uu.y << 16;
        a0 += wi[i] * c0.f;
        a1 += wi[i] * c1.f;
    }
    u16* orow = o + (size_t)row * C_DIM;
    ushort2 ov;
    ov.x = f2bf(a0); ov.y = f2bf(a1);
    *(ushort2*)(orow + c) = ov;
}

__global__ void sentinel_kernel(float* out) {
    if (threadIdx.x == 0 && blockIdx.x == 0) out[0] = 12345.0f;
}

extern "C" void kernel_launch(void* const* d_in, const int* in_sizes, int n_in,
                              void* d_out, int out_size, void* d_ws, size_t ws_size,
                              hipStream_t stream) {
    (void)in_sizes; (void)n_in; (void)out_size;
    const float* x  = (const float*)d_in[0];
    const float* gw = (const float*)d_in[1];
    const float* gb = (const float*)d_in[2];
    const float* wq = (const float*)d_in[3];
    const float* bq = (const float*)d_in[4];
    const float* wk = (const float*)d_in[5];
    const float* bk = (const float*)d_in[6];
    const float* wv = (const float*)d_in[7];
    const float* bv = (const float*)d_in[8];
    const float* wo = (const float*)d_in[9];
    const float* bo = (const float*)d_in[10];
    float* out = (float*)d_out;

    // ws layout (bytes):
    // stats 1K | wb 2M | h(=ob) 8M | q 8M | k 8M | vT 8M | opart(bf16) 32M | ml 256K
    const size_t REQ = 69469184;
    if (ws_size < REQ) {
        sentinel_kernel<<<1, 64, 0, stream>>>(out);
        return;
    }
    char* ws = (char*)d_ws;
    float* stats = (float*)ws;
    u16* wb  = (u16*)(ws + 1024);
    u16* h   = (u16*)(ws + 1024 + 2097152);
    u16* qb  = h + (size_t)8192 * 512;
    u16* kb  = qb + (size_t)8192 * 512;
    u16* vTb = kb + (size_t)8192 * 512;
    u16* opart = vTb + (size_t)8192 * 512;            // 2*4*4096*512 bf16 = 32MB
    float* ml = (float*)((char*)opart + (size_t)33554432);
    u16* ob = h;                                      // reuse h after proj0

    gn_wconv_kernel<<<1088, 256, 0, stream>>>(x, wq, wk, wv, wo, stats, wb);
    hnorm_kernel<<<dim3(64, 16, 2), 256, 0, stream>>>(x, stats, gw, gb, h);
    proj_kernel<0><<<dim3(64, 12), 256, 0, stream>>>(h, wb, bq, bk, bv, qb, kb, vTb,
                                                     nullptr, nullptr);
    flash_kernel<<<256, 512, 0, stream>>>(qb, kb, vTb, opart, ml);
    merge_kernel<<<8192, 256, 0, stream>>>(opart, ml, ob);
    proj_kernel<1><<<dim3(64, 4), 256, 0, stream>>>(ob, wb + (size_t)3 * 262144, bo, nullptr,
                                                    nullptr, nullptr, nullptr, nullptr, x, out);
}

// Round 11
// 173.161 us; speedup vs baseline: 1.1800x; 1.1052x over previous
//
#include <hip/hip_runtime.h>
#include <hip/hip_bf16.h>
#include <stdint.h>

#define S_LEN 4096
#define C_DIM 512
#define NGROUPS 32
#define EPS_GN 1e-5f
#define QSCALE 0.044194173824159216f   // 512^-0.5

typedef float f32x4 __attribute__((ext_vector_type(4)));
typedef float f32x16 __attribute__((ext_vector_type(16)));
typedef __bf16 bf16x8 __attribute__((ext_vector_type(8)));
typedef unsigned short u16;
typedef unsigned int u32;

__device__ __forceinline__ u16 f2bf(float f) {
    union { float f; u32 u; } v; v.f = f;
    u32 r = v.u + 0x7FFFu + ((v.u >> 16) & 1u);
    return (u16)(r >> 16);
}
__device__ __forceinline__ u32 pack2(float a, float b) {
    return (u32)f2bf(a) | ((u32)f2bf(b) << 16);
}

// async global->LDS 16B per lane; LDS dest is wave-uniform base + lane*16
__device__ __forceinline__ void async16(const void* g, void* l) {
    __builtin_amdgcn_global_load_lds((const __attribute__((address_space(1))) u32*)g,
                                     (__attribute__((address_space(3))) u32*)l, 16, 0, 0);
}

#define BARRIER() do { asm volatile("" ::: "memory"); __builtin_amdgcn_s_barrier(); asm volatile("" ::: "memory"); } while (0)
#define WAIT_LGKM0() asm volatile("s_waitcnt lgkmcnt(0)" ::: "memory")
#define WAIT_VM0()   asm volatile("s_waitcnt vmcnt(0)" ::: "memory")

// ---------------- fused GroupNorm partial stats + weight fp32->bf16 ----------------
// blocks [0,256): partial (S,SS) for quarter-of-(b,g); blocks [256,1280): weight conversion
__global__ __launch_bounds__(256) void gn_wconv_kernel(const float* __restrict__ x,
                                                       const float* __restrict__ wq,
                                                       const float* __restrict__ wk,
                                                       const float* __restrict__ wv,
                                                       const float* __restrict__ wo,
                                                       float* __restrict__ pstats,
                                                       u16* __restrict__ wb) {
    const int tid = threadIdx.x;
    if (blockIdx.x >= 256) {
        const int i = (blockIdx.x - 256) * 256 + tid;  // 262144 float4 total
        const int m = i >> 16;
        const int j = i & 65535;
        const float* src = (m == 0) ? wq : (m == 1) ? wk : (m == 2) ? wv : wo;
        const float4 v = ((const float4*)src)[j];
        ushort4 o;
        o.x = f2bf(v.x); o.y = f2bf(v.y); o.z = f2bf(v.z); o.w = f2bf(v.w);
        ((ushort4*)wb)[i] = o;
        return;
    }
    // partial reduce: 16384 floats per block (quarter of a 64K-element group)
    const float* p = x + (size_t)blockIdx.x * 16384;
    float s = 0.f, ss = 0.f;
#pragma unroll
    for (int it = 0; it < 16; ++it) {
        const float4 v = ((const float4*)p)[it * 256 + tid];
        s += v.x + v.y + v.z + v.w;
        ss += v.x * v.x + v.y * v.y + v.z * v.z + v.w * v.w;
    }
#pragma unroll
    for (int off = 32; off > 0; off >>= 1) {
        s += __shfl_down(s, off);
        ss += __shfl_down(ss, off);
    }
    __shared__ float rs_[4], rss_[4];
    if ((tid & 63) == 0) { rs_[tid >> 6] = s; rss_[tid >> 6] = ss; }
    __syncthreads();
    if (tid == 0) {
        pstats[blockIdx.x * 2 + 0] = rs_[0] + rs_[1] + rs_[2] + rs_[3];
        pstats[blockIdx.x * 2 + 1] = rss_[0] + rss_[1] + rss_[2] + rss_[3];
    }
}

// ---------------- normalize + transpose to h[b][s][c] bf16 (finalizes stats) ----------------
__global__ __launch_bounds__(256) void hnorm_kernel(const float* __restrict__ x,
                                                    const float* __restrict__ pstats,
                                                    const float* __restrict__ gw,
                                                    const float* __restrict__ gb,
                                                    u16* __restrict__ h) {
    __shared__ float tile[32][65];
    const int b = blockIdx.z, c0 = blockIdx.y * 32, s0 = blockIdx.x * 64;
    const int tid = threadIdx.x;
#pragma unroll
    for (int kq = 0; kq < 2; ++kq) {
        const int f = tid + kq * 256;
        const int c = f >> 4, cs = f & 15;
        const float4 v = *(const float4*)(x + ((size_t)(b * C_DIM + c0 + c) * S_LEN + s0 + cs * 4));
        const int g = (c0 + c) >> 4;
        const float* pp = pstats + (size_t)(b * NGROUPS + g) * 8;
        const float S  = (pp[0] + pp[2]) + (pp[4] + pp[6]);
        const float SS = (pp[1] + pp[3]) + (pp[5] + pp[7]);
        const float mean = S * (1.f / 65536.f);
        const float rstd = rsqrtf(SS * (1.f / 65536.f) - mean * mean + EPS_GN);
        const float a = rstd * gw[c0 + c];
        const float be = gb[c0 + c] - mean * a;
        tile[c][cs * 4 + 0] = v.x * a + be;
        tile[c][cs * 4 + 1] = v.y * a + be;
        tile[c][cs * 4 + 2] = v.z * a + be;
        tile[c][cs * 4 + 3] = v.w * a + be;
    }
    __syncthreads();
#pragma unroll
    for (int kq = 0; kq < 2; ++kq) {
        const int f = tid + kq * 256;
        const int s = f >> 3, c4 = f & 7;
        ushort4 o;
        o.x = f2bf(tile[c4 * 4 + 0][s]);
        o.y = f2bf(tile[c4 * 4 + 1][s]);
        o.z = f2bf(tile[c4 * 4 + 2][s]);
        o.w = f2bf(tile[c4 * 4 + 3][s]);
        *(ushort4*)(h + ((size_t)(b * S_LEN + s0 + s) * C_DIM + c0 + c4 * 4)) = o;
    }
}

// ---------------- 128x128 GEMM, BK=32 double-buffered pipeline ----------------
// MODE 0: QKV projection (nt selects q/k/v); MODE 1: out projection + residual.
// LDS 32 KB = As0|Bs0|As1|Bs1 (8 KB each); stage(t+1) flies across compute(t).
// Epilogue reuses the 32 KB for coalesced stores.
template <int MODE>
__global__ __launch_bounds__(256) void proj_kernel(
    const u16* __restrict__ A, const u16* __restrict__ W,
    const float* __restrict__ bias0, const float* __restrict__ bias1,
    const float* __restrict__ bias2,
    u16* __restrict__ oq, u16* __restrict__ ok_, u16* __restrict__ ovT,
    const float* __restrict__ xres, float* __restrict__ out) {
    __shared__ u16 SMEM[16384];                 // 32 KB

    const int mt = blockIdx.x;
    const int nt = blockIdx.y;
    const int m0 = mt * 128;
    const int which = (MODE == 0) ? (nt >> 2) : 0;
    const int n0 = (MODE == 0) ? ((nt & 3) * 128) : (nt * 128);

    const u16* Ab = A + (size_t)m0 * C_DIM;
    const u16* Bb = W + (size_t)which * (C_DIM * C_DIM) + (size_t)n0 * C_DIM;

    const int tid = threadIdx.x;
    const int w = tid >> 6, l = tid & 63, lr = l & 15, lg = l >> 4;
    const int wr = (w >> 1) * 64, wc = (w & 1) * 64;

    f32x4 acc[4][4];
#pragma unroll
    for (int i = 0; i < 4; ++i)
#pragma unroll
        for (int j = 0; j < 4; ++j) acc[i][j] = (f32x4){0.f, 0.f, 0.f, 0.f};

    // staging: chunk ch = w*2+i covers rows [ch*16, ch*16+16) x 32 cols (1 KB).
    // lane l -> row = ch*16 + (l>>2), granule pos g = l&3 holds source granule g ^ ((row>>1)&3).
#define STAGE(P, K0)                                                                     \
    do {                                                                                 \
        u16* const Asp_ = SMEM + (P) * 8192;                                             \
        u16* const Bsp_ = Asp_ + 4096;                                                   \
        _Pragma("unroll") for (int i = 0; i < 2; ++i) {                                  \
            const int ch = w * 2 + i;                                                    \
            const int row = ch * 16 + (l >> 2);                                          \
            const int sg = (l & 3) ^ ((row >> 1) & 3);                                   \
            async16(Ab + (size_t)row * C_DIM + (K0) + sg * 8, (void*)(Asp_ + ch * 512)); \
        }                                                                                \
        _Pragma("unroll") for (int i = 0; i < 2; ++i) {                                  \
            const int ch = w * 2 + i;                                                    \
            const int row = ch * 16 + (l >> 2);                                          \
            const int sg = (l & 3) ^ ((row >> 1) & 3);                                   \
            async16(Bb + (size_t)row * C_DIM + (K0) + sg * 8, (void*)(Bsp_ + ch * 512)); \
        }                                                                                \
    } while (0)

    STAGE(0, 0);
    WAIT_VM0();
    BARRIER();

    for (int t = 0; t < 16; ++t) {
        const int p = t & 1;
        if (t < 15) STAGE(p ^ 1, (t + 1) * 32);
        const u16* Asp = SMEM + p * 8192;
        const u16* Bsp = Asp + 4096;
        bf16x8 af[4], bfr[4];
#pragma unroll
        for (int i = 0; i < 4; ++i) {
            const int row = wr + i * 16 + lr;
            const int g = lg ^ ((row >> 1) & 3);
            af[i] = *(const bf16x8*)(Asp + row * 32 + g * 8);
        }
#pragma unroll
        for (int j = 0; j < 4; ++j) {
            const int row = wc + j * 16 + lr;
            const int g = lg ^ ((row >> 1) & 3);
            bfr[j] = *(const bf16x8*)(Bsp + row * 32 + g * 8);
        }
#pragma unroll
        for (int i = 0; i < 4; ++i)
#pragma unroll
            for (int j = 0; j < 4; ++j)
                acc[i][j] = __builtin_amdgcn_mfma_f32_16x16x32_bf16(af[i], bfr[j], acc[i][j], 0, 0, 0);
        asm volatile("s_waitcnt vmcnt(0) lgkmcnt(0)" ::: "memory");
        BARRIER();
    }
#undef STAGE

    if (MODE == 0) {
        const float* bias = (which == 0) ? bias0 : (which == 1 ? bias1 : bias2);
        u16* const Ct = SMEM;                      // 128x128 bf16 = 32 KB
#pragma unroll
        for (int j = 0; j < 4; ++j) {
            const int gcl = wc + j * 16 + lr;
            const float bv = bias[n0 + gcl];
#pragma unroll
            for (int i = 0; i < 4; ++i) {
#pragma unroll
                for (int r = 0; r < 4; ++r) {
                    const int grl = wr + i * 16 + lg * 4 + r;
                    float v = acc[i][j][r] + bv;
                    if (which == 0) v *= QSCALE;
                    const u16 hv = f2bf(v);
                    if (which < 2)
                        Ct[grl * 128 + gcl] = hv;                      // row-major
                    else                                               // transposed + XOR swizzle
                        *(u16*)((char*)Ct + gcl * 256 + ((grl * 2) ^ ((gcl & 7) << 4))) = hv;
                }
            }
        }
        __syncthreads();
        if (which < 2) {
            u16* const dst = (which == 0) ? oq : ok_;
#pragma unroll
            for (int it = 0; it < 8; ++it) {
                const int e = it * 256 + tid;
                const int row = e >> 4, c8 = e & 15;
                const uint4 val = *(const uint4*)(Ct + row * 128 + c8 * 8);
                *(uint4*)(dst + (size_t)(m0 + row) * C_DIM + n0 + c8 * 8) = val;
            }
        } else {
            const int b0 = m0 >> 12, s0 = m0 & (S_LEN - 1);
#pragma unroll
            for (int it = 0; it < 8; ++it) {
                const int e = it * 256 + tid;
                const int crow = e >> 4, c8 = e & 15;
                const uint4 val = *(const uint4*)((char*)Ct + crow * 256 + ((c8 * 16) ^ ((crow & 7) << 4)));
                *(uint4*)(ovT + ((size_t)(b0 * C_DIM + n0 + crow)) * S_LEN + s0 + c8 * 8) = val;
            }
        }
    } else {
        // MODE 1: transposed f32 + residual, two 64-channel passes through 32 KB LDS
        float* const Ctf = (float*)SMEM;           // [64 ch][128 s] f32, XOR-swizzled
        const int b0 = m0 >> 12, s0 = m0 & (S_LEN - 1);
#pragma unroll
        for (int pass = 0; pass < 2; ++pass) {
            if ((w & 1) == pass) {
#pragma unroll
                for (int j = 0; j < 4; ++j) {
                    const int gcl = j * 16 + lr;   // 0..63 within this half
                    const float bv = bias0[n0 + pass * 64 + gcl];
#pragma unroll
                    for (int i = 0; i < 4; ++i) {
#pragma unroll
                        for (int r = 0; r < 4; ++r) {
                            const int grl = wr + i * 16 + lg * 4 + r;
                            const float v = acc[i][j][r] + bv;
                            *(float*)((char*)Ctf + gcl * 512 + ((grl * 4) ^ ((gcl & 7) << 4))) = v;
                        }
                    }
                }
            }
            __syncthreads();
#pragma unroll
            for (int it = 0; it < 8; ++it) {
                const int e = it * 256 + tid;
                const int crow = e >> 5, sg = e & 31;
                const f32x4 cv = *(const f32x4*)((char*)Ctf + crow * 512 + ((sg * 16) ^ ((crow & 7) << 4)));
                const size_t gidx = ((size_t)(b0 * C_DIM + n0 + pass * 64 + crow)) * S_LEN + s0 + sg * 4;
                const f32x4 xr = *(const f32x4*)(xres + gidx);
                *(f32x4*)(out + gidx) = cv + xr;
            }
            __syncthreads();
        }
    }
}

// ---------------- flash attention: q-tile 128, 8 waves, K+V dbuf, counted vmcnt ----------------
// grid 256 (1 block/CU); 160 KB LDS: K dbuf 2x32K | V dbuf 2x32K | Sx 32K.
// Per step: [issue K(t+1)] QK(t) -> Sx b128 exchange (vmcnt(4): V(t) drained, K flying)
//           [issue V(t+1)] softmax -> cvt_pk pack -> PV(t) -> vmcnt(4): K(t+1) drained, V flying.
__global__ __launch_bounds__(512, 2) void flash_kernel(
    const u16* __restrict__ q, const u16* __restrict__ k, const u16* __restrict__ vT,
    u16* __restrict__ opart, float* __restrict__ ml) {
    __shared__ u16 LDSU[81920];                 // 160 KB exactly
    float* const Sx = (float*)(LDSU + 65536);   // bytes [131072, 163840)

    const int bid = blockIdx.x;
    const int wgid = (bid & 7) * 32 + (bid >> 3);   // XCD swizzle: one (b,sp) per XCD
    const int qt = wgid & 31;
    const int sp = (wgid >> 5) & 3;
    const int b = wgid >> 7;
    const int m0 = qt * 128;
    const int tbeg = sp * 1024;

    const int tid = threadIdx.x;
    const int w = tid >> 6;
    const int l = tid & 63;
    const int rg = w >> 1;            // q row-group (32 rows)
    const int h = w & 1;              // c-half (QK) / d-half (PV)
    const int ln = l & 31;
    const int hi = l >> 5;

    // Q as B-fragments (swapped QK^T), c-half per wave
    bf16x8 qf[16];
    {
        const u16* qrow = q + ((size_t)(b * S_LEN) + m0 + rg * 32 + ln) * C_DIM + h * 256 + hi * 8;
#pragma unroll
        for (int cc = 0; cc < 16; ++cc)
            qf[cc] = *(const bf16x8*)(qrow + cc * 16);
    }

    f32x16 oacc[8];
#pragma unroll
    for (int dt = 0; dt < 8; ++dt)
#pragma unroll
        for (int r = 0; r < 16; ++r) oacc[dt][r] = 0.f;
    float rm = -3.0e38f, rl = 0.f;

    const u16* kbase = k + (size_t)b * S_LEN * C_DIM;
    const u16* vbase = vT + (size_t)b * C_DIM * S_LEN;

    // prologue: stage K(0), V(0) into parity-0 buffers; full drain once
#pragma unroll
    for (int i = 0; i < 4; ++i) {
        const int row = w * 4 + i;
        async16(kbase + (size_t)(tbeg + row) * C_DIM + ((l ^ (row & 7)) * 8),
                (void*)(LDSU + row * 512));
    }
#pragma unroll
    for (int i = 0; i < 4; ++i) {
        const int ch = w * 4 + i;
        const int d0 = ch * 16;
        const int d = d0 + (l >> 2);
        const int g = (l & 3) ^ ((d >> 1) & 3);
        async16(vbase + (size_t)d * S_LEN + tbeg + g * 8, (void*)(LDSU + 32768 + d0 * 32));
    }
    WAIT_VM0();
    BARRIER();

    for (int step = 0; step < 32; ++step) {
        const int t0 = tbeg + step * 32;
        const u16* kcur = LDSU + (step & 1) * 16384;
        const u16* vcur = LDSU + 32768 + (step & 1) * 16384;

        // issue K(t+1) into other parity (4 loads; drained at bottom vmcnt(4))
        if (step < 31) {
            u16* knxt = LDSU + ((step + 1) & 1) * 16384;
#pragma unroll
            for (int i = 0; i < 4; ++i) {
                const int row = w * 4 + i;
                async16(kbase + (size_t)(t0 + 32 + row) * C_DIM + ((l ^ (row & 7)) * 8),
                        (void*)(knxt + row * 512));
            }
        }

        // S^T = K(c-half) * Q^T : 16 MFMA from prefetched K
        f32x16 sa;
#pragma unroll
        for (int r = 0; r < 16; ++r) sa[r] = 0.f;
        __builtin_amdgcn_s_setprio(1);
#pragma unroll
        for (int cc = 0; cc < 16; ++cc) {
            const int g = h * 32 + cc * 2 + hi;
            const bf16x8 af = *(const bf16x8*)(kcur + ln * 512 + ((g ^ (ln & 7)) * 8));
            sa = __builtin_amdgcn_mfma_f32_32x32x16_bf16(af, qf[cc], sa, 0, 0, 0);
        }
        __builtin_amdgcn_s_setprio(0);

        // Sx exchange with partner wave (w^1): [wave][chunk][lane] f32x4, b128 ops
        {
            float* swb = Sx + w * 1024 + l * 4;
#pragma unroll
            for (int c = 0; c < 4; ++c)
                *(f32x4*)(swb + c * 256) = (f32x4){sa[c * 4 + 0], sa[c * 4 + 1], sa[c * 4 + 2], sa[c * 4 + 3]};
            // B1: own Sx writes done (lgkm); V(t) landed for all waves (vmcnt: drain oldest 4 = V(t), K(t+1) stays)
            if (step < 31) { asm volatile("s_waitcnt vmcnt(4) lgkmcnt(0)" ::: "memory"); }
            else           { asm volatile("s_waitcnt vmcnt(0) lgkmcnt(0)" ::: "memory"); }
            BARRIER();
            const float* prb = Sx + (w ^ 1) * 1024 + l * 4;
#pragma unroll
            for (int c = 0; c < 4; ++c) {
                const f32x4 pv = *(const f32x4*)(prb + c * 256);
                sa[c * 4 + 0] += pv[0];
                sa[c * 4 + 1] += pv[1];
                sa[c * 4 + 2] += pv[2];
                sa[c * 4 + 3] += pv[3];
            }
        }

        // issue V(t+1) into other parity (4 loads; in flight across PV + bottom barrier)
        if (step < 31) {
            u16* vnxt = LDSU + 32768 + ((step + 1) & 1) * 16384;
#pragma unroll
            for (int i = 0; i < 4; ++i) {
                const int ch = w * 4 + i;
                const int d0 = ch * 16;
                const int d = d0 + (l >> 2);
                const int g = (l & 3) ^ ((d >> 1) & 3);
                async16(vbase + (size_t)d * S_LEN + t0 + 32 + g * 8, (void*)(vnxt + d0 * 32));
            }
        }

        // online softmax (lane owns one q column; tree reductions)
        float t8[8];
#pragma unroll
        for (int r = 0; r < 8; ++r) t8[r] = fmaxf(sa[r], sa[r + 8]);
#pragma unroll
        for (int r = 0; r < 4; ++r) t8[r] = fmaxf(t8[r], t8[r + 4]);
        float pm = fmaxf(fmaxf(t8[0], t8[1]), fmaxf(t8[2], t8[3]));
        pm = fmaxf(pm, __shfl_xor(pm, 32));
        if (!__all(pm <= rm + 8.f)) {          // T13 defer-max (rarely triggers)
            const float mn = fmaxf(rm, pm);
            const float al = __expf(rm - mn);
            rl *= al;
#pragma unroll
            for (int dt = 0; dt < 8; ++dt)
#pragma unroll
                for (int r = 0; r < 16; ++r) oacc[dt][r] *= al;
            rm = mn;
        }
#pragma unroll
        for (int r = 0; r < 16; ++r) sa[r] = __expf(sa[r] - rm);
        {
            float s8[8];
#pragma unroll
            for (int r = 0; r < 8; ++r) s8[r] = sa[r] + sa[r + 8];
#pragma unroll
            for (int r = 0; r < 4; ++r) s8[r] += s8[r + 4];
            float rs = (s8[0] + s8[1]) + (s8[2] + s8[3]);
            rs += __shfl_xor(rs, 32);
            rl += rs;
        }

        // pack P to bf16 via v_cvt_pk (T12); redistribute across lane halves
        u32 wv[8], pw[8];
#pragma unroll
        for (int s4 = 0; s4 < 4; ++s4) {
            asm("v_cvt_pk_bf16_f32 %0, %1, %2" : "=v"(wv[s4 * 2 + 0]) : "v"(sa[s4 * 4 + 0]), "v"(sa[s4 * 4 + 1]));
            asm("v_cvt_pk_bf16_f32 %0, %1, %2" : "=v"(wv[s4 * 2 + 1]) : "v"(sa[s4 * 4 + 2]), "v"(sa[s4 * 4 + 3]));
        }
#pragma unroll
        for (int j = 0; j < 8; ++j) pw[j] = __shfl_xor((int)wv[j], 32);
        union { u32 u[4]; bf16x8 v; } pb0, pb1;
        pb0.u[0] = hi ? pw[2] : wv[0];
        pb0.u[1] = hi ? pw[3] : wv[1];
        pb0.u[2] = hi ? wv[2] : pw[0];
        pb0.u[3] = hi ? wv[3] : pw[1];
        pb1.u[0] = hi ? pw[6] : wv[4];
        pb1.u[1] = hi ? pw[7] : wv[5];
        pb1.u[2] = hi ? wv[6] : pw[4];
        pb1.u[3] = hi ? wv[7] : pw[5];

        // O^T += V^T * P^T from prefetched V (landed & barrier'd at B1)
        __builtin_amdgcn_s_setprio(1);
#pragma unroll
        for (int dt = 0; dt < 8; ++dt) {
            const int d = h * 256 + dt * 32 + ln;
#pragma unroll
            for (int kk = 0; kk < 2; ++kk) {
                const int slot = (kk * 2 + hi) ^ ((d >> 1) & 3);
                const bf16x8 vf = *(const bf16x8*)(vcur + d * 32 + slot * 8);
                oacc[dt] = __builtin_amdgcn_mfma_f32_32x32x16_bf16(vf, kk ? pb1.v : pb0.v, oacc[dt], 0, 0, 0);
            }
        }
        __builtin_amdgcn_s_setprio(0);

        // bottom: own LDS reads done; K(t+1) landed (drain oldest 4, V(t+1) keeps flying)
        asm volatile("s_waitcnt vmcnt(4) lgkmcnt(0)" ::: "memory");
        BARRIER();
    }

    // epilogue: normalize, transpose via LDS (reuse K+V region), coalesced store
    const float inv = 1.f / rl;
    u16* const Ot = LDSU;  // [128 q][512 d] bf16, 16B-granule XOR swizzle by (q&7)
    {
        const int qq = rg * 32 + ln;
#pragma unroll
        for (int dt = 0; dt < 8; ++dt) {
#pragma unroll
            for (int u = 0; u < 8; ++u) {
                const int d = h * 256 + dt * 32 + (((2 * u) & 3) + 8 * (u >> 1) + 4 * hi);
                const u32 word = pack2(oacc[dt][2 * u] * inv, oacc[dt][2 * u + 1] * inv);
                const int byte = qq * 1024 + ((d * 2) ^ ((qq & 7) << 4));
                *(u32*)((char*)Ot + byte) = word;
            }
        }
    }
    if (h == 0 && hi == 0) {
        float* mlp = ml + (size_t)((b * 4 + sp) * 2) * S_LEN;
        mlp[m0 + rg * 32 + ln] = rm;
        mlp[S_LEN + m0 + rg * 32 + ln] = rl;
    }
    WAIT_LGKM0();
    BARRIER();
    {
        u16* od = opart + ((size_t)((b * 4 + sp) * S_LEN) + m0) * C_DIM;
#pragma unroll
        for (int i = 0; i < 16; ++i) {
            const int qq = w * 16 + i;
            const int byte = qq * 1024 + ((l * 16) ^ ((qq & 7) << 4));
            const uint4 tv = *(const uint4*)((char*)Ot + byte);
            *(uint4*)(od + (size_t)qq * C_DIM + l * 8) = tv;
        }
    }
}

// ---------------- merge the four KV-split partials (normalized bf16 + m,l) ----------------
__global__ __launch_bounds__(256) void merge_kernel(const u16* __restrict__ opart,
                                                    const float* __restrict__ ml,
                                                    u16* __restrict__ o) {
    const int row = blockIdx.x;  // b*4096 + s
    const int b = row >> 12, s = row & 4095;
    float mi[4], li[4];
#pragma unroll
    for (int i = 0; i < 4; ++i) {
        const float* mlp = ml + (size_t)((b * 4 + i) * 2) * S_LEN;
        mi[i] = mlp[s];
        li[i] = mlp[S_LEN + s];
    }
    float mm = fmaxf(fmaxf(mi[0], mi[1]), fmaxf(mi[2], mi[3]));
    float wsum = 0.f, wi[4];
#pragma unroll
    for (int i = 0; i < 4; ++i) { wi[i] = __expf(mi[i] - mm) * li[i]; wsum += wi[i]; }
    const float invw = 1.f / wsum;
#pragma unroll
    for (int i = 0; i < 4; ++i) wi[i] *= invw;

    const int c = threadIdx.x * 2;
    float a0 = 0.f, a1 = 0.f;
#pragma unroll
    for (int i = 0; i < 4; ++i) {
        const u16* p = opart + ((size_t)((b * 4 + i) * S_LEN) + s) * C_DIM + c;
        const ushort2 uu = *(const ushort2*)p;
        union { u32 u; float f; } c0, c1;
        c0.u = (u32)uu.x << 16; c1.u = (u32)uu.y << 16;
        a0 += wi[i] * c0.f;
        a1 += wi[i] * c1.f;
    }
    u16* orow = o + (size_t)row * C_DIM;
    ushort2 ov;
    ov.x = f2bf(a0); ov.y = f2bf(a1);
    *(ushort2*)(orow + c) = ov;
}

__global__ void sentinel_kernel(float* out) {
    if (threadIdx.x == 0 && blockIdx.x == 0) out[0] = 12345.0f;
}

extern "C" void kernel_launch(void* const* d_in, const int* in_sizes, int n_in,
                              void* d_out, int out_size, void* d_ws, size_t ws_size,
                              hipStream_t stream) {
    (void)in_sizes; (void)n_in; (void)out_size;
    const float* x  = (const float*)d_in[0];
    const float* gw = (const float*)d_in[1];
    const float* gb = (const float*)d_in[2];
    const float* wq = (const float*)d_in[3];
    const float* bq = (const float*)d_in[4];
    const float* wk = (const float*)d_in[5];
    const float* bk = (const float*)d_in[6];
    const float* wv = (const float*)d_in[7];
    const float* bv = (const float*)d_in[8];
    const float* wo = (const float*)d_in[9];
    const float* bo = (const float*)d_in[10];
    float* out = (float*)d_out;

    // ws layout (bytes):
    // (reserved) 1K | wb 2M | h(=ob) 8M | q 8M | k 8M | vT 8M | opart(bf16) 32M | ml 256K
    // gn partial stats (2 KB) borrow the ml region (free until flash writes it).
    const size_t REQ = 69469184;
    if (ws_size < REQ) {
        sentinel_kernel<<<1, 64, 0, stream>>>(out);
        return;
    }
    char* ws = (char*)d_ws;
    u16* wb  = (u16*)(ws + 1024);
    u16* h   = (u16*)(ws + 1024 + 2097152);
    u16* qb  = h + (size_t)8192 * 512;
    u16* kb  = qb + (size_t)8192 * 512;
    u16* vTb = kb + (size_t)8192 * 512;
    u16* opart = vTb + (size_t)8192 * 512;            // 2*4*4096*512 bf16 = 32MB
    float* ml = (float*)((char*)opart + (size_t)33554432);
    float* pstats = ml;                                // 512 floats, consumed before flash
    u16* ob = h;                                      // reuse h after proj0

    gn_wconv_kernel<<<1280, 256, 0, stream>>>(x, wq, wk, wv, wo, pstats, wb);
    hnorm_kernel<<<dim3(64, 16, 2), 256, 0, stream>>>(x, pstats, gw, gb, h);
    proj_kernel<0><<<dim3(64, 12), 256, 0, stream>>>(h, wb, bq, bk, bv, qb, kb, vTb,
                                                     nullptr, nullptr);
    flash_kernel<<<256, 512, 0, stream>>>(qb, kb, vTb, opart, ml);
    merge_kernel<<<8192, 256, 0, stream>>>(opart, ml, ob);
    proj_kernel<1><<<dim3(64, 4), 256, 0, stream>>>(ob, wb + (size_t)3 * 262144, bo, nullptr,
                                                    nullptr, nullptr, nullptr, nullptr, x, out);
}

// Round 12
// 165.977 us; speedup vs baseline: 1.2310x; 1.0433x over previous
//
#include <hip/hip_runtime.h>
#include <hip/hip_bf16.h>
#include <stdint.h>

#define S_LEN 4096
#define C_DIM 512
#define NGROUPS 32
#define EPS_GN 1e-5f
#define QSCALE 0.044194173824159216f   // 512^-0.5

typedef float f32x4 __attribute__((ext_vector_type(4)));
typedef float f32x16 __attribute__((ext_vector_type(16)));
typedef __bf16 bf16x8 __attribute__((ext_vector_type(8)));
typedef unsigned short u16;
typedef unsigned int u32;

__device__ __forceinline__ u16 f2bf(float f) {
    union { float f; u32 u; } v; v.f = f;
    u32 r = v.u + 0x7FFFu + ((v.u >> 16) & 1u);
    return (u16)(r >> 16);
}
__device__ __forceinline__ u32 pack2(float a, float b) {
    return (u32)f2bf(a) | ((u32)f2bf(b) << 16);
}

// async global->LDS 16B per lane; LDS dest is wave-uniform base + lane*16
__device__ __forceinline__ void async16(const void* g, void* l) {
    __builtin_amdgcn_global_load_lds((const __attribute__((address_space(1))) u32*)g,
                                     (__attribute__((address_space(3))) u32*)l, 16, 0, 0);
}

#define BARRIER() do { asm volatile("" ::: "memory"); __builtin_amdgcn_s_barrier(); asm volatile("" ::: "memory"); } while (0)
#define WAIT_LGKM0() asm volatile("s_waitcnt lgkmcnt(0)" ::: "memory")
#define WAIT_VM0()   asm volatile("s_waitcnt vmcnt(0)" ::: "memory")

// ---------------- fused GroupNorm partial stats + weight fp32->bf16 ----------------
// blocks [0,256): partial (S,SS) for quarter-of-(b,g); blocks [256,1280): weight conversion
__global__ __launch_bounds__(256) void gn_wconv_kernel(const float* __restrict__ x,
                                                       const float* __restrict__ wq,
                                                       const float* __restrict__ wk,
                                                       const float* __restrict__ wv,
                                                       const float* __restrict__ wo,
                                                       float* __restrict__ pstats,
                                                       u16* __restrict__ wb) {
    const int tid = threadIdx.x;
    if (blockIdx.x >= 256) {
        const int i = (blockIdx.x - 256) * 256 + tid;  // 262144 float4 total
        const int m = i >> 16;
        const int j = i & 65535;
        const float* src = (m == 0) ? wq : (m == 1) ? wk : (m == 2) ? wv : wo;
        const float4 v = ((const float4*)src)[j];
        ushort4 o;
        o.x = f2bf(v.x); o.y = f2bf(v.y); o.z = f2bf(v.z); o.w = f2bf(v.w);
        ((ushort4*)wb)[i] = o;
        return;
    }
    // partial reduce: 16384 floats per block (quarter of a 64K-element group)
    const float* p = x + (size_t)blockIdx.x * 16384;
    float s = 0.f, ss = 0.f;
#pragma unroll
    for (int it = 0; it < 16; ++it) {
        const float4 v = ((const float4*)p)[it * 256 + tid];
        s += v.x + v.y + v.z + v.w;
        ss += v.x * v.x + v.y * v.y + v.z * v.z + v.w * v.w;
    }
#pragma unroll
    for (int off = 32; off > 0; off >>= 1) {
        s += __shfl_down(s, off);
        ss += __shfl_down(ss, off);
    }
    __shared__ float rs_[4], rss_[4];
    if ((tid & 63) == 0) { rs_[tid >> 6] = s; rss_[tid >> 6] = ss; }
    __syncthreads();
    if (tid == 0) {
        pstats[blockIdx.x * 2 + 0] = rs_[0] + rs_[1] + rs_[2] + rs_[3];
        pstats[blockIdx.x * 2 + 1] = rss_[0] + rss_[1] + rss_[2] + rss_[3];
    }
}

// ---------------- normalize + transpose to h[b][s][c] bf16 (finalizes stats) ----------------
__global__ __launch_bounds__(256) void hnorm_kernel(const float* __restrict__ x,
                                                    const float* __restrict__ pstats,
                                                    const float* __restrict__ gw,
                                                    const float* __restrict__ gb,
                                                    u16* __restrict__ h) {
    __shared__ float tile[32][65];
    const int b = blockIdx.z, c0 = blockIdx.y * 32, s0 = blockIdx.x * 64;
    const int tid = threadIdx.x;
#pragma unroll
    for (int kq = 0; kq < 2; ++kq) {
        const int f = tid + kq * 256;
        const int c = f >> 4, cs = f & 15;
        const float4 v = *(const float4*)(x + ((size_t)(b * C_DIM + c0 + c) * S_LEN + s0 + cs * 4));
        const int g = (c0 + c) >> 4;
        const float* pp = pstats + (size_t)(b * NGROUPS + g) * 8;
        const float S  = (pp[0] + pp[2]) + (pp[4] + pp[6]);
        const float SS = (pp[1] + pp[3]) + (pp[5] + pp[7]);
        const float mean = S * (1.f / 65536.f);
        const float rstd = rsqrtf(SS * (1.f / 65536.f) - mean * mean + EPS_GN);
        const float a = rstd * gw[c0 + c];
        const float be = gb[c0 + c] - mean * a;
        tile[c][cs * 4 + 0] = v.x * a + be;
        tile[c][cs * 4 + 1] = v.y * a + be;
        tile[c][cs * 4 + 2] = v.z * a + be;
        tile[c][cs * 4 + 3] = v.w * a + be;
    }
    __syncthreads();
#pragma unroll
    for (int kq = 0; kq < 2; ++kq) {
        const int f = tid + kq * 256;
        const int s = f >> 3, c4 = f & 7;
        ushort4 o;
        o.x = f2bf(tile[c4 * 4 + 0][s]);
        o.y = f2bf(tile[c4 * 4 + 1][s]);
        o.z = f2bf(tile[c4 * 4 + 2][s]);
        o.w = f2bf(tile[c4 * 4 + 3][s]);
        *(ushort4*)(h + ((size_t)(b * S_LEN + s0 + s) * C_DIM + c0 + c4 * 4)) = o;
    }
}

// ---------------- 128x128 GEMM, BK=32, 3-stage pipeline (counted vmcnt) ----------------
// MODE 0: QKV projection (nt selects q/k/v); MODE 1: out projection + residual.
// LDS 48 KB = 3 x (As 8K | Bs 8K); stage(t+2) issued at step t -> ~2 steps to land.
// Epilogue reuses the first 32 KB for coalesced stores.
template <int MODE>
__global__ __launch_bounds__(256) void proj_kernel(
    const u16* __restrict__ A, const u16* __restrict__ W,
    const float* __restrict__ bias0, const float* __restrict__ bias1,
    const float* __restrict__ bias2,
    u16* __restrict__ oq, u16* __restrict__ ok_, u16* __restrict__ ovT,
    const float* __restrict__ xres, float* __restrict__ out) {
    __shared__ u16 SMEM[24576];                 // 48 KB

    const int mt = blockIdx.x;
    const int nt = blockIdx.y;
    const int m0 = mt * 128;
    const int which = (MODE == 0) ? (nt >> 2) : 0;
    const int n0 = (MODE == 0) ? ((nt & 3) * 128) : (nt * 128);

    const u16* Ab = A + (size_t)m0 * C_DIM;
    const u16* Bb = W + (size_t)which * (C_DIM * C_DIM) + (size_t)n0 * C_DIM;

    const int tid = threadIdx.x;
    const int w = tid >> 6, l = tid & 63, lr = l & 15, lg = l >> 4;
    const int wr = (w >> 1) * 64, wc = (w & 1) * 64;

    f32x4 acc[4][4];
#pragma unroll
    for (int i = 0; i < 4; ++i)
#pragma unroll
        for (int j = 0; j < 4; ++j) acc[i][j] = (f32x4){0.f, 0.f, 0.f, 0.f};

    // staging: chunk ch = w*2+i covers rows [ch*16, ch*16+16) x 32 cols (1 KB).
    // lane l -> row = ch*16 + (l>>2), granule pos g = l&3 holds source granule g ^ ((row>>1)&3).
    // 4 loads per wave per STAGE (2 A + 2 B) -> vmcnt counts in units of 4.
#define STAGE(S, K0)                                                                     \
    do {                                                                                 \
        u16* const Asp_ = SMEM + (S) * 8192;                                             \
        u16* const Bsp_ = Asp_ + 4096;                                                   \
        _Pragma("unroll") for (int i = 0; i < 2; ++i) {                                  \
            const int ch = w * 2 + i;                                                    \
            const int row = ch * 16 + (l >> 2);                                          \
            const int sg = (l & 3) ^ ((row >> 1) & 3);                                   \
            async16(Ab + (size_t)row * C_DIM + (K0) + sg * 8, (void*)(Asp_ + ch * 512)); \
        }                                                                                \
        _Pragma("unroll") for (int i = 0; i < 2; ++i) {                                  \
            const int ch = w * 2 + i;                                                    \
            const int row = ch * 16 + (l >> 2);                                          \
            const int sg = (l & 3) ^ ((row >> 1) & 3);                                   \
            async16(Bb + (size_t)row * C_DIM + (K0) + sg * 8, (void*)(Bsp_ + ch * 512)); \
        }                                                                                \
    } while (0)

    STAGE(0, 0);
    STAGE(1, 32);
    asm volatile("s_waitcnt vmcnt(4)" ::: "memory");   // stage 0 landed, stage 1 flying
    BARRIER();

    for (int t = 0; t < 16; ++t) {
        const int s = t % 3;
        if (t < 14) STAGE((t + 2) % 3, (t + 2) * 32);
        const u16* Asp = SMEM + s * 8192;
        const u16* Bsp = Asp + 4096;
        bf16x8 af[4], bfr[4];
#pragma unroll
        for (int i = 0; i < 4; ++i) {
            const int row = wr + i * 16 + lr;
            const int g = lg ^ ((row >> 1) & 3);
            af[i] = *(const bf16x8*)(Asp + row * 32 + g * 8);
        }
#pragma unroll
        for (int j = 0; j < 4; ++j) {
            const int row = wc + j * 16 + lr;
            const int g = lg ^ ((row >> 1) & 3);
            bfr[j] = *(const bf16x8*)(Bsp + row * 32 + g * 8);
        }
#pragma unroll
        for (int i = 0; i < 4; ++i)
#pragma unroll
            for (int j = 0; j < 4; ++j)
                acc[i][j] = __builtin_amdgcn_mfma_f32_16x16x32_bf16(af[i], bfr[j], acc[i][j], 0, 0, 0);
        // bottom: stage(t+1) landed (oldest 4 of 8 in flight), stage(t+2) keeps flying
        if (t < 14) { asm volatile("s_waitcnt vmcnt(4) lgkmcnt(0)" ::: "memory"); }
        else        { asm volatile("s_waitcnt vmcnt(0) lgkmcnt(0)" ::: "memory"); }
        BARRIER();
    }
#undef STAGE

    if (MODE == 0) {
        const float* bias = (which == 0) ? bias0 : (which == 1 ? bias1 : bias2);
        u16* const Ct = SMEM;                      // 128x128 bf16 = 32 KB
#pragma unroll
        for (int j = 0; j < 4; ++j) {
            const int gcl = wc + j * 16 + lr;
            const float bv = bias[n0 + gcl];
#pragma unroll
            for (int i = 0; i < 4; ++i) {
#pragma unroll
                for (int r = 0; r < 4; ++r) {
                    const int grl = wr + i * 16 + lg * 4 + r;
                    float v = acc[i][j][r] + bv;
                    if (which == 0) v *= QSCALE;
                    const u16 hv = f2bf(v);
                    if (which < 2)
                        Ct[grl * 128 + gcl] = hv;                      // row-major
                    else                                               // transposed + XOR swizzle
                        *(u16*)((char*)Ct + gcl * 256 + ((grl * 2) ^ ((gcl & 7) << 4))) = hv;
                }
            }
        }
        __syncthreads();
        if (which < 2) {
            u16* const dst = (which == 0) ? oq : ok_;
#pragma unroll
            for (int it = 0; it < 8; ++it) {
                const int e = it * 256 + tid;
                const int row = e >> 4, c8 = e & 15;
                const uint4 val = *(const uint4*)(Ct + row * 128 + c8 * 8);
                *(uint4*)(dst + (size_t)(m0 + row) * C_DIM + n0 + c8 * 8) = val;
            }
        } else {
            const int b0 = m0 >> 12, s0 = m0 & (S_LEN - 1);
#pragma unroll
            for (int it = 0; it < 8; ++it) {
                const int e = it * 256 + tid;
                const int crow = e >> 4, c8 = e & 15;
                const uint4 val = *(const uint4*)((char*)Ct + crow * 256 + ((c8 * 16) ^ ((crow & 7) << 4)));
                *(uint4*)(ovT + ((size_t)(b0 * C_DIM + n0 + crow)) * S_LEN + s0 + c8 * 8) = val;
            }
        }
    } else {
        // MODE 1: transposed f32 + residual, two 64-channel passes through 32 KB LDS
        float* const Ctf = (float*)SMEM;           // [64 ch][128 s] f32, XOR-swizzled
        const int b0 = m0 >> 12, s0 = m0 & (S_LEN - 1);
#pragma unroll
        for (int pass = 0; pass < 2; ++pass) {
            if ((w & 1) == pass) {
#pragma unroll
                for (int j = 0; j < 4; ++j) {
                    const int gcl = j * 16 + lr;   // 0..63 within this half
                    const float bv = bias0[n0 + pass * 64 + gcl];
#pragma unroll
                    for (int i = 0; i < 4; ++i) {
#pragma unroll
                        for (int r = 0; r < 4; ++r) {
                            const int grl = wr + i * 16 + lg * 4 + r;
                            const float v = acc[i][j][r] + bv;
                            *(float*)((char*)Ctf + gcl * 512 + ((grl * 4) ^ ((gcl & 7) << 4))) = v;
                        }
                    }
                }
            }
            __syncthreads();
#pragma unroll
            for (int it = 0; it < 8; ++it) {
                const int e = it * 256 + tid;
                const int crow = e >> 5, sg = e & 31;
                const f32x4 cv = *(const f32x4*)((char*)Ctf + crow * 512 + ((sg * 16) ^ ((crow & 7) << 4)));
                const size_t gidx = ((size_t)(b0 * C_DIM + n0 + pass * 64 + crow)) * S_LEN + s0 + sg * 4;
                const f32x4 xr = *(const f32x4*)(xres + gidx);
                *(f32x4*)(out + gidx) = cv + xr;
            }
            __syncthreads();
        }
    }
}

// ---------------- flash attention: q-tile 128, 8 waves, K+V dbuf, counted vmcnt ----------------
// grid 256 (1 block/CU); 160 KB LDS: K dbuf 2x32K | V dbuf 2x32K | Sx 32K.
// Per step: [issue K(t+1)] QK(t) -> Sx b128 exchange (vmcnt(4): V(t) drained, K flying)
//           [issue V(t+1)] softmax -> cvt_pk pack -> PV(t) -> vmcnt(4): K(t+1) drained, V flying.
__global__ __launch_bounds__(512, 2) void flash_kernel(
    const u16* __restrict__ q, const u16* __restrict__ k, const u16* __restrict__ vT,
    u16* __restrict__ opart, float* __restrict__ ml) {
    __shared__ u16 LDSU[81920];                 // 160 KB exactly
    float* const Sx = (float*)(LDSU + 65536);   // bytes [131072, 163840)

    const int bid = blockIdx.x;
    const int wgid = (bid & 7) * 32 + (bid >> 3);   // XCD swizzle: one (b,sp) per XCD
    const int qt = wgid & 31;
    const int sp = (wgid >> 5) & 3;
    const int b = wgid >> 7;
    const int m0 = qt * 128;
    const int tbeg = sp * 1024;

    const int tid = threadIdx.x;
    const int w = tid >> 6;
    const int l = tid & 63;
    const int rg = w >> 1;            // q row-group (32 rows)
    const int h = w & 1;              // c-half (QK) / d-half (PV)
    const int ln = l & 31;
    const int hi = l >> 5;

    // Q as B-fragments (swapped QK^T), c-half per wave
    bf16x8 qf[16];
    {
        const u16* qrow = q + ((size_t)(b * S_LEN) + m0 + rg * 32 + ln) * C_DIM + h * 256 + hi * 8;
#pragma unroll
        for (int cc = 0; cc < 16; ++cc)
            qf[cc] = *(const bf16x8*)(qrow + cc * 16);
    }

    f32x16 oacc[8];
#pragma unroll
    for (int dt = 0; dt < 8; ++dt)
#pragma unroll
        for (int r = 0; r < 16; ++r) oacc[dt][r] = 0.f;
    float rm = -3.0e38f, rl = 0.f;

    const u16* kbase = k + (size_t)b * S_LEN * C_DIM;
    const u16* vbase = vT + (size_t)b * C_DIM * S_LEN;

    // prologue: stage K(0), V(0) into parity-0 buffers; full drain once
#pragma unroll
    for (int i = 0; i < 4; ++i) {
        const int row = w * 4 + i;
        async16(kbase + (size_t)(tbeg + row) * C_DIM + ((l ^ (row & 7)) * 8),
                (void*)(LDSU + row * 512));
    }
#pragma unroll
    for (int i = 0; i < 4; ++i) {
        const int ch = w * 4 + i;
        const int d0 = ch * 16;
        const int d = d0 + (l >> 2);
        const int g = (l & 3) ^ ((d >> 1) & 3);
        async16(vbase + (size_t)d * S_LEN + tbeg + g * 8, (void*)(LDSU + 32768 + d0 * 32));
    }
    WAIT_VM0();
    BARRIER();

    for (int step = 0; step < 32; ++step) {
        const int t0 = tbeg + step * 32;
        const u16* kcur = LDSU + (step & 1) * 16384;
        const u16* vcur = LDSU + 32768 + (step & 1) * 16384;

        // issue K(t+1) into other parity (4 loads; drained at bottom vmcnt(4))
        if (step < 31) {
            u16* knxt = LDSU + ((step + 1) & 1) * 16384;
#pragma unroll
            for (int i = 0; i < 4; ++i) {
                const int row = w * 4 + i;
                async16(kbase + (size_t)(t0 + 32 + row) * C_DIM + ((l ^ (row & 7)) * 8),
                        (void*)(knxt + row * 512));
            }
        }

        // S^T = K(c-half) * Q^T : 16 MFMA from prefetched K
        f32x16 sa;
#pragma unroll
        for (int r = 0; r < 16; ++r) sa[r] = 0.f;
        __builtin_amdgcn_s_setprio(1);
#pragma unroll
        for (int cc = 0; cc < 16; ++cc) {
            const int g = h * 32 + cc * 2 + hi;
            const bf16x8 af = *(const bf16x8*)(kcur + ln * 512 + ((g ^ (ln & 7)) * 8));
            sa = __builtin_amdgcn_mfma_f32_32x32x16_bf16(af, qf[cc], sa, 0, 0, 0);
        }
        __builtin_amdgcn_s_setprio(0);

        // Sx exchange with partner wave (w^1): [wave][chunk][lane] f32x4, b128 ops
        {
            float* swb = Sx + w * 1024 + l * 4;
#pragma unroll
            for (int c = 0; c < 4; ++c)
                *(f32x4*)(swb + c * 256) = (f32x4){sa[c * 4 + 0], sa[c * 4 + 1], sa[c * 4 + 2], sa[c * 4 + 3]};
            // B1: own Sx writes done (lgkm); V(t) landed for all waves (vmcnt: drain oldest 4 = V(t), K(t+1) stays)
            if (step < 31) { asm volatile("s_waitcnt vmcnt(4) lgkmcnt(0)" ::: "memory"); }
            else           { asm volatile("s_waitcnt vmcnt(0) lgkmcnt(0)" ::: "memory"); }
            BARRIER();
            const float* prb = Sx + (w ^ 1) * 1024 + l * 4;
#pragma unroll
            for (int c = 0; c < 4; ++c) {
                const f32x4 pv = *(const f32x4*)(prb + c * 256);
                sa[c * 4 + 0] += pv[0];
                sa[c * 4 + 1] += pv[1];
                sa[c * 4 + 2] += pv[2];
                sa[c * 4 + 3] += pv[3];
            }
        }

        // issue V(t+1) into other parity (4 loads; in flight across PV + bottom barrier)
        if (step < 31) {
            u16* vnxt = LDSU + 32768 + ((step + 1) & 1) * 16384;
#pragma unroll
            for (int i = 0; i < 4; ++i) {
                const int ch = w * 4 + i;
                const int d0 = ch * 16;
                const int d = d0 + (l >> 2);
                const int g = (l & 3) ^ ((d >> 1) & 3);
                async16(vbase + (size_t)d * S_LEN + t0 + 32 + g * 8, (void*)(vnxt + d0 * 32));
            }
        }

        // online softmax (lane owns one q column; tree reductions)
        float t8[8];
#pragma unroll
        for (int r = 0; r < 8; ++r) t8[r] = fmaxf(sa[r], sa[r + 8]);
#pragma unroll
        for (int r = 0; r < 4; ++r) t8[r] = fmaxf(t8[r], t8[r + 4]);
        float pm = fmaxf(fmaxf(t8[0], t8[1]), fmaxf(t8[2], t8[3]));
        pm = fmaxf(pm, __shfl_xor(pm, 32));
        if (!__all(pm <= rm + 8.f)) {          // T13 defer-max (rarely triggers)
            const float mn = fmaxf(rm, pm);
            const float al = __expf(rm - mn);
            rl *= al;
#pragma unroll
            for (int dt = 0; dt < 8; ++dt)
#pragma unroll
                for (int r = 0; r < 16; ++r) oacc[dt][r] *= al;
            rm = mn;
        }
#pragma unroll
        for (int r = 0; r < 16; ++r) sa[r] = __expf(sa[r] - rm);
        {
            float s8[8];
#pragma unroll
            for (int r = 0; r < 8; ++r) s8[r] = sa[r] + sa[r + 8];
#pragma unroll
            for (int r = 0; r < 4; ++r) s8[r] += s8[r + 4];
            float rs = (s8[0] + s8[1]) + (s8[2] + s8[3]);
            rs += __shfl_xor(rs, 32);
            rl += rs;
        }

        // pack P to bf16 via v_cvt_pk (T12); redistribute across lane halves
        u32 wv[8], pw[8];
#pragma unroll
        for (int s4 = 0; s4 < 4; ++s4) {
            asm("v_cvt_pk_bf16_f32 %0, %1, %2" : "=v"(wv[s4 * 2 + 0]) : "v"(sa[s4 * 4 + 0]), "v"(sa[s4 * 4 + 1]));
            asm("v_cvt_pk_bf16_f32 %0, %1, %2" : "=v"(wv[s4 * 2 + 1]) : "v"(sa[s4 * 4 + 2]), "v"(sa[s4 * 4 + 3]));
        }
#pragma unroll
        for (int j = 0; j < 8; ++j) pw[j] = __shfl_xor((int)wv[j], 32);
        union { u32 u[4]; bf16x8 v; } pb0, pb1;
        pb0.u[0] = hi ? pw[2] : wv[0];
        pb0.u[1] = hi ? pw[3] : wv[1];
        pb0.u[2] = hi ? wv[2] : pw[0];
        pb0.u[3] = hi ? wv[3] : pw[1];
        pb1.u[0] = hi ? pw[6] : wv[4];
        pb1.u[1] = hi ? pw[7] : wv[5];
        pb1.u[2] = hi ? wv[6] : pw[4];
        pb1.u[3] = hi ? wv[7] : pw[5];

        // O^T += V^T * P^T from prefetched V (landed & barrier'd at B1)
        __builtin_amdgcn_s_setprio(1);
#pragma unroll
        for (int dt = 0; dt < 8; ++dt) {
            const int d = h * 256 + dt * 32 + ln;
#pragma unroll
            for (int kk = 0; kk < 2; ++kk) {
                const int slot = (kk * 2 + hi) ^ ((d >> 1) & 3);
                const bf16x8 vf = *(const bf16x8*)(vcur + d * 32 + slot * 8);
                oacc[dt] = __builtin_amdgcn_mfma_f32_32x32x16_bf16(vf, kk ? pb1.v : pb0.v, oacc[dt], 0, 0, 0);
            }
        }
        __builtin_amdgcn_s_setprio(0);

        // bottom: own LDS reads done; K(t+1) landed (drain oldest 4, V(t+1) keeps flying)
        asm volatile("s_waitcnt vmcnt(4) lgkmcnt(0)" ::: "memory");
        BARRIER();
    }

    // epilogue: normalize, transpose via LDS (reuse K+V region), coalesced store
    const float inv = 1.f / rl;
    u16* const Ot = LDSU;  // [128 q][512 d] bf16, 16B-granule XOR swizzle by (q&7)
    {
        const int qq = rg * 32 + ln;
#pragma unroll
        for (int dt = 0; dt < 8; ++dt) {
#pragma unroll
            for (int u = 0; u < 8; ++u) {
                const int d = h * 256 + dt * 32 + (((2 * u) & 3) + 8 * (u >> 1) + 4 * hi);
                const u32 word = pack2(oacc[dt][2 * u] * inv, oacc[dt][2 * u + 1] * inv);
                const int byte = qq * 1024 + ((d * 2) ^ ((qq & 7) << 4));
                *(u32*)((char*)Ot + byte) = word;
            }
        }
    }
    if (h == 0 && hi == 0) {
        float* mlp = ml + (size_t)((b * 4 + sp) * 2) * S_LEN;
        mlp[m0 + rg * 32 + ln] = rm;
        mlp[S_LEN + m0 + rg * 32 + ln] = rl;
    }
    WAIT_LGKM0();
    BARRIER();
    {
        u16* od = opart + ((size_t)((b * 4 + sp) * S_LEN) + m0) * C_DIM;
#pragma unroll
        for (int i = 0; i < 16; ++i) {
            const int qq = w * 16 + i;
            const int byte = qq * 1024 + ((l * 16) ^ ((qq & 7) << 4));
            const uint4 tv = *(const uint4*)((char*)Ot + byte);
            *(uint4*)(od + (size_t)qq * C_DIM + l * 8) = tv;
        }
    }
}

// ---------------- merge the four KV-split partials (normalized bf16 + m,l) ----------------
__global__ __launch_bounds__(256) void merge_kernel(const u16* __restrict__ opart,
                                                    const float* __restrict__ ml,
                                                    u16* __restrict__ o) {
    const int row = blockIdx.x;  // b*4096 + s
    const int b = row >> 12, s = row & 4095;
    float mi[4], li[4];
#pragma unroll
    for (int i = 0; i < 4; ++i) {
        const float* mlp = ml + (size_t)((b * 4 + i) * 2) * S_LEN;
        mi[i] = mlp[s];
        li[i] = mlp[S_LEN + s];
    }
    float mm = fmaxf(fmaxf(mi[0], mi[1]), fmaxf(mi[2], mi[3]));
    float wsum = 0.f, wi[4];
#pragma unroll
    for (int i = 0; i < 4; ++i) { wi[i] = __expf(mi[i] - mm) * li[i]; wsum += wi[i]; }
    const float invw = 1.f / wsum;
#pragma unroll
    for (int i = 0; i < 4; ++i) wi[i] *= invw;

    const int c = threadIdx.x * 2;
    float a0 = 0.f, a1 = 0.f;
#pragma unroll
    for (int i = 0; i < 4; ++i) {
        const u16* p = opart + ((size_t)((b * 4 + i) * S_LEN) + s) * C_DIM + c;
        const ushort2 uu = *(const ushort2*)p;
        union { u32 u; float f; } c0, c1;
        c0.u = (u32)uu.x << 16; c1.u = (u32)uu.y << 16;
        a0 += wi[i] * c0.f;
        a1 += wi[i] * c1.f;
    }
    u16* orow = o + (size_t)row * C_DIM;
    ushort2 ov;
    ov.x = f2bf(a0); ov.y = f2bf(a1);
    *(ushort2*)(orow + c) = ov;
}

__global__ void sentinel_kernel(float* out) {
    if (threadIdx.x == 0 && blockIdx.x == 0) out[0] = 12345.0f;
}

extern "C" void kernel_launch(void* const* d_in, const int* in_sizes, int n_in,
                              void* d_out, int out_size, void* d_ws, size_t ws_size,
                              hipStream_t stream) {
    (void)in_sizes; (void)n_in; (void)out_size;
    const float* x  = (const float*)d_in[0];
    const float* gw = (const float*)d_in[1];
    const float* gb = (const float*)d_in[2];
    const float* wq = (const float*)d_in[3];
    const float* bq = (const float*)d_in[4];
    const float* wk = (const float*)d_in[5];
    const float* bk = (const float*)d_in[6];
    const float* wv = (const float*)d_in[7];
    const float* bv = (const float*)d_in[8];
    const float* wo = (const float*)d_in[9];
    const float* bo = (const float*)d_in[10];
    float* out = (float*)d_out;

    // ws layout (bytes):
    // (reserved) 1K | wb 2M | h(=ob) 8M | q 8M | k 8M | vT 8M | opart(bf16) 32M | ml 256K
    // gn partial stats (2 KB) borrow the ml region (free until flash writes it).
    const size_t REQ = 69469184;
    if (ws_size < REQ) {
        sentinel_kernel<<<1, 64, 0, stream>>>(out);
        return;
    }
    char* ws = (char*)d_ws;
    u16* wb  = (u16*)(ws + 1024);
    u16* h   = (u16*)(ws + 1024 + 2097152);
    u16* qb  = h + (size_t)8192 * 512;
    u16* kb  = qb + (size_t)8192 * 512;
    u16* vTb = kb + (size_t)8192 * 512;
    u16* opart = vTb + (size_t)8192 * 512;            // 2*4*4096*512 bf16 = 32MB
    float* ml = (float*)((char*)opart + (size_t)33554432);
    float* pstats = ml;                                // 512 floats, consumed before flash
    u16* ob = h;                                      // reuse h after proj0

    gn_wconv_kernel<<<1280, 256, 0, stream>>>(x, wq, wk, wv, wo, pstats, wb);
    hnorm_kernel<<<dim3(64, 16, 2), 256, 0, stream>>>(x, pstats, gw, gb, h);
    proj_kernel<0><<<dim3(64, 12), 256, 0, stream>>>(h, wb, bq, bk, bv, qb, kb, vTb,
                                                     nullptr, nullptr);
    flash_kernel<<<256, 512, 0, stream>>>(qb, kb, vTb, opart, ml);
    merge_kernel<<<8192, 256, 0, stream>>>(opart, ml, ob);
    proj_kernel<1><<<dim3(64, 4), 256, 0, stream>>>(ob, wb + (size_t)3 * 262144, bo, nullptr,
                                                    nullptr, nullptr, nullptr, nullptr, x, out);
}

// Round 13
// 163.683 us; speedup vs baseline: 1.2483x; 1.0140x over previous
//
#include <hip/hip_runtime.h>
#include <hip/hip_bf16.h>
#include <stdint.h>

#define S_LEN 4096
#define C_DIM 512
#define NGROUPS 32
#define EPS_GN 1e-5f
#define QSCALE 0.044194173824159216f   // 512^-0.5

typedef float f32x4 __attribute__((ext_vector_type(4)));
typedef float f32x16 __attribute__((ext_vector_type(16)));
typedef __bf16 bf16x8 __attribute__((ext_vector_type(8)));
typedef unsigned short u16;
typedef unsigned int u32;

__device__ __forceinline__ u16 f2bf(float f) {
    union { float f; u32 u; } v; v.f = f;
    u32 r = v.u + 0x7FFFu + ((v.u >> 16) & 1u);
    return (u16)(r >> 16);
}
__device__ __forceinline__ u32 pack2(float a, float b) {
    return (u32)f2bf(a) | ((u32)f2bf(b) << 16);
}

// async global->LDS 16B per lane; LDS dest is wave-uniform base + lane*16
__device__ __forceinline__ void async16(const void* g, void* l) {
    __builtin_amdgcn_global_load_lds((const __attribute__((address_space(1))) u32*)g,
                                     (__attribute__((address_space(3))) u32*)l, 16, 0, 0);
}

#define BARRIER() do { asm volatile("" ::: "memory"); __builtin_amdgcn_s_barrier(); asm volatile("" ::: "memory"); } while (0)
#define WAIT_LGKM0() asm volatile("s_waitcnt lgkmcnt(0)" ::: "memory")
#define WAIT_VM0()   asm volatile("s_waitcnt vmcnt(0)" ::: "memory")

// ---------------- fused GroupNorm partial stats + weight fp32->bf16 ----------------
// blocks [0,256): partial (S,SS) for quarter-of-(b,g); blocks [256,1280): weight conversion
__global__ __launch_bounds__(256) void gn_wconv_kernel(const float* __restrict__ x,
                                                       const float* __restrict__ wq,
                                                       const float* __restrict__ wk,
                                                       const float* __restrict__ wv,
                                                       const float* __restrict__ wo,
                                                       float* __restrict__ pstats,
                                                       u16* __restrict__ wb) {
    const int tid = threadIdx.x;
    if (blockIdx.x >= 256) {
        const int i = (blockIdx.x - 256) * 256 + tid;  // 262144 float4 total
        const int m = i >> 16;
        const int j = i & 65535;
        const float* src = (m == 0) ? wq : (m == 1) ? wk : (m == 2) ? wv : wo;
        const float4 v = ((const float4*)src)[j];
        ushort4 o;
        o.x = f2bf(v.x); o.y = f2bf(v.y); o.z = f2bf(v.z); o.w = f2bf(v.w);
        ((ushort4*)wb)[i] = o;
        return;
    }
    // partial reduce: 16384 floats per block (quarter of a 64K-element group)
    const float* p = x + (size_t)blockIdx.x * 16384;
    float s = 0.f, ss = 0.f;
#pragma unroll
    for (int it = 0; it < 16; ++it) {
        const float4 v = ((const float4*)p)[it * 256 + tid];
        s += v.x + v.y + v.z + v.w;
        ss += v.x * v.x + v.y * v.y + v.z * v.z + v.w * v.w;
    }
#pragma unroll
    for (int off = 32; off > 0; off >>= 1) {
        s += __shfl_down(s, off);
        ss += __shfl_down(ss, off);
    }
    __shared__ float rs_[4], rss_[4];
    if ((tid & 63) == 0) { rs_[tid >> 6] = s; rss_[tid >> 6] = ss; }
    __syncthreads();
    if (tid == 0) {
        pstats[blockIdx.x * 2 + 0] = rs_[0] + rs_[1] + rs_[2] + rs_[3];
        pstats[blockIdx.x * 2 + 1] = rss_[0] + rss_[1] + rss_[2] + rss_[3];
    }
}

// ---------------- normalize + transpose to h[b][s][c] bf16 (finalizes stats) ----------------
__global__ __launch_bounds__(256) void hnorm_kernel(const float* __restrict__ x,
                                                    const float* __restrict__ pstats,
                                                    const float* __restrict__ gw,
                                                    const float* __restrict__ gb,
                                                    u16* __restrict__ h) {
    __shared__ float tile[32][65];
    const int b = blockIdx.z, c0 = blockIdx.y * 32, s0 = blockIdx.x * 64;
    const int tid = threadIdx.x;
#pragma unroll
    for (int kq = 0; kq < 2; ++kq) {
        const int f = tid + kq * 256;
        const int c = f >> 4, cs = f & 15;
        const float4 v = *(const float4*)(x + ((size_t)(b * C_DIM + c0 + c) * S_LEN + s0 + cs * 4));
        const int g = (c0 + c) >> 4;
        const float* pp = pstats + (size_t)(b * NGROUPS + g) * 8;
        const float S  = (pp[0] + pp[2]) + (pp[4] + pp[6]);
        const float SS = (pp[1] + pp[3]) + (pp[5] + pp[7]);
        const float mean = S * (1.f / 65536.f);
        const float rstd = rsqrtf(SS * (1.f / 65536.f) - mean * mean + EPS_GN);
        const float a = rstd * gw[c0 + c];
        const float be = gb[c0 + c] - mean * a;
        tile[c][cs * 4 + 0] = v.x * a + be;
        tile[c][cs * 4 + 1] = v.y * a + be;
        tile[c][cs * 4 + 2] = v.z * a + be;
        tile[c][cs * 4 + 3] = v.w * a + be;
    }
    __syncthreads();
#pragma unroll
    for (int kq = 0; kq < 2; ++kq) {
        const int f = tid + kq * 256;
        const int s = f >> 3, c4 = f & 7;
        ushort4 o;
        o.x = f2bf(tile[c4 * 4 + 0][s]);
        o.y = f2bf(tile[c4 * 4 + 1][s]);
        o.z = f2bf(tile[c4 * 4 + 2][s]);
        o.w = f2bf(tile[c4 * 4 + 3][s]);
        *(ushort4*)(h + ((size_t)(b * S_LEN + s0 + s) * C_DIM + c0 + c4 * 4)) = o;
    }
}

// ---------------- 128x128 GEMM, BK=32, 3-stage pipeline (counted vmcnt) ----------------
// MODE 0: QKV projection (nt selects q/k/v); MODE 1: out projection + residual.
// LDS 48 KB = 3 x (As 8K | Bs 8K); stage(t+2) issued at step t -> ~2 steps to land.
// Epilogue reuses the first 32 KB for coalesced stores.
template <int MODE>
__global__ __launch_bounds__(256) void proj_kernel(
    const u16* __restrict__ A, const u16* __restrict__ W,
    const float* __restrict__ bias0, const float* __restrict__ bias1,
    const float* __restrict__ bias2,
    u16* __restrict__ oq, u16* __restrict__ ok_, u16* __restrict__ ovT,
    const float* __restrict__ xres, float* __restrict__ out) {
    __shared__ u16 SMEM[24576];                 // 48 KB

    const int mt = blockIdx.x;
    const int nt = blockIdx.y;
    const int m0 = mt * 128;
    const int which = (MODE == 0) ? (nt >> 2) : 0;
    const int n0 = (MODE == 0) ? ((nt & 3) * 128) : (nt * 128);

    const u16* Ab = A + (size_t)m0 * C_DIM;
    const u16* Bb = W + (size_t)which * (C_DIM * C_DIM) + (size_t)n0 * C_DIM;

    const int tid = threadIdx.x;
    const int w = tid >> 6, l = tid & 63, lr = l & 15, lg = l >> 4;
    const int wr = (w >> 1) * 64, wc = (w & 1) * 64;

    f32x4 acc[4][4];
#pragma unroll
    for (int i = 0; i < 4; ++i)
#pragma unroll
        for (int j = 0; j < 4; ++j) acc[i][j] = (f32x4){0.f, 0.f, 0.f, 0.f};

    // staging: chunk ch = w*2+i covers rows [ch*16, ch*16+16) x 32 cols (1 KB).
    // lane l -> row = ch*16 + (l>>2), granule pos g = l&3 holds source granule g ^ ((row>>1)&3).
    // 4 loads per wave per STAGE (2 A + 2 B) -> vmcnt counts in units of 4.
#define STAGE(S, K0)                                                                     \
    do {                                                                                 \
        u16* const Asp_ = SMEM + (S) * 8192;                                             \
        u16* const Bsp_ = Asp_ + 4096;                                                   \
        _Pragma("unroll") for (int i = 0; i < 2; ++i) {                                  \
            const int ch = w * 2 + i;                                                    \
            const int row = ch * 16 + (l >> 2);                                          \
            const int sg = (l & 3) ^ ((row >> 1) & 3);                                   \
            async16(Ab + (size_t)row * C_DIM + (K0) + sg * 8, (void*)(Asp_ + ch * 512)); \
        }                                                                                \
        _Pragma("unroll") for (int i = 0; i < 2; ++i) {                                  \
            const int ch = w * 2 + i;                                                    \
            const int row = ch * 16 + (l >> 2);                                          \
            const int sg = (l & 3) ^ ((row >> 1) & 3);                                   \
            async16(Bb + (size_t)row * C_DIM + (K0) + sg * 8, (void*)(Bsp_ + ch * 512)); \
        }                                                                                \
    } while (0)

    STAGE(0, 0);
    STAGE(1, 32);
    asm volatile("s_waitcnt vmcnt(4)" ::: "memory");   // stage 0 landed, stage 1 flying
    BARRIER();

    for (int t = 0; t < 16; ++t) {
        const int s = t % 3;
        if (t < 14) STAGE((t + 2) % 3, (t + 2) * 32);
        const u16* Asp = SMEM + s * 8192;
        const u16* Bsp = Asp + 4096;
        bf16x8 af[4], bfr[4];
#pragma unroll
        for (int i = 0; i < 4; ++i) {
            const int row = wr + i * 16 + lr;
            const int g = lg ^ ((row >> 1) & 3);
            af[i] = *(const bf16x8*)(Asp + row * 32 + g * 8);
        }
#pragma unroll
        for (int j = 0; j < 4; ++j) {
            const int row = wc + j * 16 + lr;
            const int g = lg ^ ((row >> 1) & 3);
            bfr[j] = *(const bf16x8*)(Bsp + row * 32 + g * 8);
        }
#pragma unroll
        for (int i = 0; i < 4; ++i)
#pragma unroll
            for (int j = 0; j < 4; ++j)
                acc[i][j] = __builtin_amdgcn_mfma_f32_16x16x32_bf16(af[i], bfr[j], acc[i][j], 0, 0, 0);
        // bottom: stage(t+1) landed (oldest 4 of 8 in flight), stage(t+2) keeps flying
        if (t < 14) { asm volatile("s_waitcnt vmcnt(4) lgkmcnt(0)" ::: "memory"); }
        else        { asm volatile("s_waitcnt vmcnt(0) lgkmcnt(0)" ::: "memory"); }
        BARRIER();
    }
#undef STAGE

    if (MODE == 0) {
        const float* bias = (which == 0) ? bias0 : (which == 1 ? bias1 : bias2);
        u16* const Ct = SMEM;                      // 128x128 bf16 = 32 KB
#pragma unroll
        for (int j = 0; j < 4; ++j) {
            const int gcl = wc + j * 16 + lr;
            const float bv = bias[n0 + gcl];
#pragma unroll
            for (int i = 0; i < 4; ++i) {
#pragma unroll
                for (int r = 0; r < 4; ++r) {
                    const int grl = wr + i * 16 + lg * 4 + r;
                    float v = acc[i][j][r] + bv;
                    if (which == 0) v *= QSCALE;
                    const u16 hv = f2bf(v);
                    if (which < 2)
                        Ct[grl * 128 + gcl] = hv;                      // row-major
                    else                                               // transposed + XOR swizzle
                        *(u16*)((char*)Ct + gcl * 256 + ((grl * 2) ^ ((gcl & 7) << 4))) = hv;
                }
            }
        }
        __syncthreads();
        if (which < 2) {
            u16* const dst = (which == 0) ? oq : ok_;
#pragma unroll
            for (int it = 0; it < 8; ++it) {
                const int e = it * 256 + tid;
                const int row = e >> 4, c8 = e & 15;
                const uint4 val = *(const uint4*)(Ct + row * 128 + c8 * 8);
                *(uint4*)(dst + (size_t)(m0 + row) * C_DIM + n0 + c8 * 8) = val;
            }
        } else {
            const int b0 = m0 >> 12, s0 = m0 & (S_LEN - 1);
#pragma unroll
            for (int it = 0; it < 8; ++it) {
                const int e = it * 256 + tid;
                const int crow = e >> 4, c8 = e & 15;
                const uint4 val = *(const uint4*)((char*)Ct + crow * 256 + ((c8 * 16) ^ ((crow & 7) << 4)));
                *(uint4*)(ovT + ((size_t)(b0 * C_DIM + n0 + crow)) * S_LEN + s0 + c8 * 8) = val;
            }
        }
    } else {
        // MODE 1: transposed f32 + residual, two 64-channel passes through 32 KB LDS
        float* const Ctf = (float*)SMEM;           // [64 ch][128 s] f32, XOR-swizzled
        const int b0 = m0 >> 12, s0 = m0 & (S_LEN - 1);
#pragma unroll
        for (int pass = 0; pass < 2; ++pass) {
            if ((w & 1) == pass) {
#pragma unroll
                for (int j = 0; j < 4; ++j) {
                    const int gcl = j * 16 + lr;   // 0..63 within this half
                    const float bv = bias0[n0 + pass * 64 + gcl];
#pragma unroll
                    for (int i = 0; i < 4; ++i) {
#pragma unroll
                        for (int r = 0; r < 4; ++r) {
                            const int grl = wr + i * 16 + lg * 4 + r;
                            const float v = acc[i][j][r] + bv;
                            *(float*)((char*)Ctf + gcl * 512 + ((grl * 4) ^ ((gcl & 7) << 4))) = v;
                        }
                    }
                }
            }
            __syncthreads();
#pragma unroll
            for (int it = 0; it < 8; ++it) {
                const int e = it * 256 + tid;
                const int crow = e >> 5, sg = e & 31;
                const f32x4 cv = *(const f32x4*)((char*)Ctf + crow * 512 + ((sg * 16) ^ ((crow & 7) << 4)));
                const size_t gidx = ((size_t)(b0 * C_DIM + n0 + pass * 64 + crow)) * S_LEN + s0 + sg * 4;
                const f32x4 xr = *(const f32x4*)(xres + gidx);
                *(f32x4*)(out + gidx) = cv + xr;
            }
            __syncthreads();
        }
    }
}

// ---------------- flash attention: q-tile 128, 8 waves, K+V dbuf, counted vmcnt ----------------
// grid 256 (1 block/CU); 160 KB LDS: K dbuf 2x32K | V dbuf 2x32K | Sx 32K.
// Per step: [issue K(t+1)] QK(t) -> Sx write -> B1(vmcnt(4): V(t) drained, K flying)
//           [issue V(t+1)] -> Sx partner read -> softmax -> cvt_pk pack -> PV(t)
//           -> vmcnt(4): K(t+1) drained, V flying.
__global__ __launch_bounds__(512, 2) void flash_kernel(
    const u16* __restrict__ q, const u16* __restrict__ k, const u16* __restrict__ vT,
    u16* __restrict__ opart, float* __restrict__ ml) {
    __shared__ u16 LDSU[81920];                 // 160 KB exactly
    float* const Sx = (float*)(LDSU + 65536);   // bytes [131072, 163840)

    const int bid = blockIdx.x;
    const int wgid = (bid & 7) * 32 + (bid >> 3);   // XCD swizzle: one (b,sp) per XCD
    const int qt = wgid & 31;
    const int sp = (wgid >> 5) & 3;
    const int b = wgid >> 7;
    const int m0 = qt * 128;
    const int tbeg = sp * 1024;

    const int tid = threadIdx.x;
    const int w = tid >> 6;
    const int l = tid & 63;
    const int rg = w >> 1;            // q row-group (32 rows)
    const int h = w & 1;              // c-half (QK) / d-half (PV)
    const int ln = l & 31;
    const int hi = l >> 5;

    // Q as B-fragments (swapped QK^T), c-half per wave
    bf16x8 qf[16];
    {
        const u16* qrow = q + ((size_t)(b * S_LEN) + m0 + rg * 32 + ln) * C_DIM + h * 256 + hi * 8;
#pragma unroll
        for (int cc = 0; cc < 16; ++cc)
            qf[cc] = *(const bf16x8*)(qrow + cc * 16);
    }

    f32x16 oacc[8];
#pragma unroll
    for (int dt = 0; dt < 8; ++dt)
#pragma unroll
        for (int r = 0; r < 16; ++r) oacc[dt][r] = 0.f;
    float rm = -3.0e38f, rl = 0.f;

    const u16* kbase = k + (size_t)b * S_LEN * C_DIM;
    const u16* vbase = vT + (size_t)b * C_DIM * S_LEN;

    // prologue: stage K(0), V(0) into parity-0 buffers; full drain once
#pragma unroll
    for (int i = 0; i < 4; ++i) {
        const int row = w * 4 + i;
        async16(kbase + (size_t)(tbeg + row) * C_DIM + ((l ^ (row & 7)) * 8),
                (void*)(LDSU + row * 512));
    }
#pragma unroll
    for (int i = 0; i < 4; ++i) {
        const int ch = w * 4 + i;
        const int d0 = ch * 16;
        const int d = d0 + (l >> 2);
        const int g = (l & 3) ^ ((d >> 1) & 3);
        async16(vbase + (size_t)d * S_LEN + tbeg + g * 8, (void*)(LDSU + 32768 + d0 * 32));
    }
    WAIT_VM0();
    BARRIER();

    for (int step = 0; step < 32; ++step) {
        const int t0 = tbeg + step * 32;
        const u16* kcur = LDSU + (step & 1) * 16384;
        const u16* vcur = LDSU + 32768 + (step & 1) * 16384;

        // issue K(t+1) into other parity (4 loads; drained at bottom vmcnt(4))
        if (step < 31) {
            u16* knxt = LDSU + ((step + 1) & 1) * 16384;
#pragma unroll
            for (int i = 0; i < 4; ++i) {
                const int row = w * 4 + i;
                async16(kbase + (size_t)(t0 + 32 + row) * C_DIM + ((l ^ (row & 7)) * 8),
                        (void*)(knxt + row * 512));
            }
        }

        // S^T = K(c-half) * Q^T : 16 MFMA from prefetched K
        f32x16 sa;
#pragma unroll
        for (int r = 0; r < 16; ++r) sa[r] = 0.f;
        __builtin_amdgcn_s_setprio(1);
#pragma unroll
        for (int cc = 0; cc < 16; ++cc) {
            const int g = h * 32 + cc * 2 + hi;
            const bf16x8 af = *(const bf16x8*)(kcur + ln * 512 + ((g ^ (ln & 7)) * 8));
            sa = __builtin_amdgcn_mfma_f32_32x32x16_bf16(af, qf[cc], sa, 0, 0, 0);
        }
        __builtin_amdgcn_s_setprio(0);

        // Sx write (partial S), then B1
        {
            float* swb = Sx + w * 1024 + l * 4;
#pragma unroll
            for (int c = 0; c < 4; ++c)
                *(f32x4*)(swb + c * 256) = (f32x4){sa[c * 4 + 0], sa[c * 4 + 1], sa[c * 4 + 2], sa[c * 4 + 3]};
            // B1: own Sx writes done (lgkm); V(t) landed for all waves (vmcnt: drain oldest 4 = V(t), K(t+1) stays)
            if (step < 31) { asm volatile("s_waitcnt vmcnt(4) lgkmcnt(0)" ::: "memory"); }
            else           { asm volatile("s_waitcnt vmcnt(0) lgkmcnt(0)" ::: "memory"); }
            BARRIER();
        }

        // issue V(t+1) immediately after B1 (max flight time across softmax + PV)
        if (step < 31) {
            u16* vnxt = LDSU + 32768 + ((step + 1) & 1) * 16384;
#pragma unroll
            for (int i = 0; i < 4; ++i) {
                const int ch = w * 4 + i;
                const int d0 = ch * 16;
                const int d = d0 + (l >> 2);
                const int g = (l & 3) ^ ((d >> 1) & 3);
                async16(vbase + (size_t)d * S_LEN + t0 + 32 + g * 8, (void*)(vnxt + d0 * 32));
            }
        }

        // Sx partner read (published at B1)
        {
            const float* prb = Sx + (w ^ 1) * 1024 + l * 4;
#pragma unroll
            for (int c = 0; c < 4; ++c) {
                const f32x4 pv = *(const f32x4*)(prb + c * 256);
                sa[c * 4 + 0] += pv[0];
                sa[c * 4 + 1] += pv[1];
                sa[c * 4 + 2] += pv[2];
                sa[c * 4 + 3] += pv[3];
            }
        }

        // online softmax (lane owns one q column; tree reductions)
        float t8[8];
#pragma unroll
        for (int r = 0; r < 8; ++r) t8[r] = fmaxf(sa[r], sa[r + 8]);
#pragma unroll
        for (int r = 0; r < 4; ++r) t8[r] = fmaxf(t8[r], t8[r + 4]);
        float pm = fmaxf(fmaxf(t8[0], t8[1]), fmaxf(t8[2], t8[3]));
        pm = fmaxf(pm, __shfl_xor(pm, 32));
        if (!__all(pm <= rm + 8.f)) {          // T13 defer-max (rarely triggers)
            const float mn = fmaxf(rm, pm);
            const float al = __expf(rm - mn);
            rl *= al;
#pragma unroll
            for (int dt = 0; dt < 8; ++dt)
#pragma unroll
                for (int r = 0; r < 16; ++r) oacc[dt][r] *= al;
            rm = mn;
        }
#pragma unroll
        for (int r = 0; r < 16; ++r) sa[r] = __expf(sa[r] - rm);
        {
            float s8[8];
#pragma unroll
            for (int r = 0; r < 8; ++r) s8[r] = sa[r] + sa[r + 8];
#pragma unroll
            for (int r = 0; r < 4; ++r) s8[r] += s8[r + 4];
            float rs = (s8[0] + s8[1]) + (s8[2] + s8[3]);
            rs += __shfl_xor(rs, 32);
            rl += rs;
        }

        // pack P to bf16 via v_cvt_pk (T12); redistribute across lane halves
        u32 wv[8], pw[8];
#pragma unroll
        for (int s4 = 0; s4 < 4; ++s4) {
            asm("v_cvt_pk_bf16_f32 %0, %1, %2" : "=v"(wv[s4 * 2 + 0]) : "v"(sa[s4 * 4 + 0]), "v"(sa[s4 * 4 + 1]));
            asm("v_cvt_pk_bf16_f32 %0, %1, %2" : "=v"(wv[s4 * 2 + 1]) : "v"(sa[s4 * 4 + 2]), "v"(sa[s4 * 4 + 3]));
        }
#pragma unroll
        for (int j = 0; j < 8; ++j) pw[j] = __shfl_xor((int)wv[j], 32);
        union { u32 u[4]; bf16x8 v; } pb0, pb1;
        pb0.u[0] = hi ? pw[2] : wv[0];
        pb0.u[1] = hi ? pw[3] : wv[1];
        pb0.u[2] = hi ? wv[2] : pw[0];
        pb0.u[3] = hi ? wv[3] : pw[1];
        pb1.u[0] = hi ? pw[6] : wv[4];
        pb1.u[1] = hi ? pw[7] : wv[5];
        pb1.u[2] = hi ? wv[6] : pw[4];
        pb1.u[3] = hi ? wv[7] : pw[5];

        // O^T += V^T * P^T from prefetched V (landed & barrier'd at B1)
        __builtin_amdgcn_s_setprio(1);
#pragma unroll
        for (int dt = 0; dt < 8; ++dt) {
            const int d = h * 256 + dt * 32 + ln;
#pragma unroll
            for (int kk = 0; kk < 2; ++kk) {
                const int slot = (kk * 2 + hi) ^ ((d >> 1) & 3);
                const bf16x8 vf = *(const bf16x8*)(vcur + d * 32 + slot * 8);
                oacc[dt] = __builtin_amdgcn_mfma_f32_32x32x16_bf16(vf, kk ? pb1.v : pb0.v, oacc[dt], 0, 0, 0);
            }
        }
        __builtin_amdgcn_s_setprio(0);

        // bottom: own LDS reads done; K(t+1) landed (drain oldest 4, V(t+1) keeps flying)
        asm volatile("s_waitcnt vmcnt(4) lgkmcnt(0)" ::: "memory");
        BARRIER();
    }

    // epilogue: normalize, transpose via LDS (reuse K+V region), coalesced store
    const float inv = 1.f / rl;
    u16* const Ot = LDSU;  // [128 q][512 d] bf16, 16B-granule XOR swizzle by (q&7)
    {
        const int qq = rg * 32 + ln;
#pragma unroll
        for (int dt = 0; dt < 8; ++dt) {
#pragma unroll
            for (int u = 0; u < 8; ++u) {
                const int d = h * 256 + dt * 32 + (((2 * u) & 3) + 8 * (u >> 1) + 4 * hi);
                const u32 word = pack2(oacc[dt][2 * u] * inv, oacc[dt][2 * u + 1] * inv);
                const int byte = qq * 1024 + ((d * 2) ^ ((qq & 7) << 4));
                *(u32*)((char*)Ot + byte) = word;
            }
        }
    }
    if (h == 0 && hi == 0) {
        float* mlp = ml + (size_t)((b * 4 + sp) * 2) * S_LEN;
        mlp[m0 + rg * 32 + ln] = rm;
        mlp[S_LEN + m0 + rg * 32 + ln] = rl;
    }
    WAIT_LGKM0();
    BARRIER();
    {
        u16* od = opart + ((size_t)((b * 4 + sp) * S_LEN) + m0) * C_DIM;
#pragma unroll
        for (int i = 0; i < 16; ++i) {
            const int qq = w * 16 + i;
            const int byte = qq * 1024 + ((l * 16) ^ ((qq & 7) << 4));
            const uint4 tv = *(const uint4*)((char*)Ot + byte);
            *(uint4*)(od + (size_t)qq * C_DIM + l * 8) = tv;
        }
    }
}

// ---------------- merge the four KV-split partials (normalized bf16 + m,l) ----------------
// grid 2048 x 256: block handles 4 rows; thread handles 8 channels (uint4 loads/stores).
__global__ __launch_bounds__(256) void merge_kernel(const u16* __restrict__ opart,
                                                    const float* __restrict__ ml,
                                                    u16* __restrict__ o) {
    const int tid = threadIdx.x;
    const int row = blockIdx.x * 4 + (tid >> 6);  // b*4096 + s
    const int b = row >> 12, s = row & 4095;
    const int c = (tid & 63) * 8;
    float mi[4], li[4];
#pragma unroll
    for (int i = 0; i < 4; ++i) {
        const float* mlp = ml + (size_t)((b * 4 + i) * 2) * S_LEN;
        mi[i] = mlp[s];
        li[i] = mlp[S_LEN + s];
    }
    float mm = fmaxf(fmaxf(mi[0], mi[1]), fmaxf(mi[2], mi[3]));
    float wsum = 0.f, wi[4];
#pragma unroll
    for (int i = 0; i < 4; ++i) { wi[i] = __expf(mi[i] - mm) * li[i]; wsum += wi[i]; }
    const float invw = 1.f / wsum;
#pragma unroll
    for (int i = 0; i < 4; ++i) wi[i] *= invw;

    float a[8];
#pragma unroll
    for (int j = 0; j < 8; ++j) a[j] = 0.f;
#pragma unroll
    for (int i = 0; i < 4; ++i) {
        const u16* p = opart + ((size_t)((b * 4 + i) * S_LEN) + s) * C_DIM + c;
        const uint4 uu = *(const uint4*)p;
        const u32 uw[4] = {uu.x, uu.y, uu.z, uu.w};
#pragma unroll
        for (int j = 0; j < 4; ++j) {
            union { u32 u; float f; } lo, hh;
            lo.u = (uw[j] & 0xFFFFu) << 16;
            hh.u = uw[j] & 0xFFFF0000u;
            a[j * 2 + 0] += wi[i] * lo.f;
            a[j * 2 + 1] += wi[i] * hh.f;
        }
    }
    uint4 ov;
    u32* ovp = (u32*)&ov;
#pragma unroll
    for (int j = 0; j < 4; ++j) ovp[j] = pack2(a[j * 2], a[j * 2 + 1]);
    *(uint4*)(o + (size_t)row * C_DIM + c) = ov;
}

__global__ void sentinel_kernel(float* out) {
    if (threadIdx.x == 0 && blockIdx.x == 0) out[0] = 12345.0f;
}

extern "C" void kernel_launch(void* const* d_in, const int* in_sizes, int n_in,
                              void* d_out, int out_size, void* d_ws, size_t ws_size,
                              hipStream_t stream) {
    (void)in_sizes; (void)n_in; (void)out_size;
    const float* x  = (const float*)d_in[0];
    const float* gw = (const float*)d_in[1];
    const float* gb = (const float*)d_in[2];
    const float* wq = (const float*)d_in[3];
    const float* bq = (const float*)d_in[4];
    const float* wk = (const float*)d_in[5];
    const float* bk = (const float*)d_in[6];
    const float* wv = (const float*)d_in[7];
    const float* bv = (const float*)d_in[8];
    const float* wo = (const float*)d_in[9];
    const float* bo = (const float*)d_in[10];
    float* out = (float*)d_out;

    // ws layout (bytes):
    // (reserved) 1K | wb 2M | h(=ob) 8M | q 8M | k 8M | vT 8M | opart(bf16) 32M | ml 256K
    // gn partial stats (2 KB) borrow the ml region (free until flash writes it).
    const size_t REQ = 69469184;
    if (ws_size < REQ) {
        sentinel_kernel<<<1, 64, 0, stream>>>(out);
        return;
    }
    char* ws = (char*)d_ws;
    u16* wb  = (u16*)(ws + 1024);
    u16* h   = (u16*)(ws + 1024 + 2097152);
    u16* qb  = h + (size_t)8192 * 512;
    u16* kb  = qb + (size_t)8192 * 512;
    u16* vTb = kb + (size_t)8192 * 512;
    u16* opart = vTb + (size_t)8192 * 512;            // 2*4*4096*512 bf16 = 32MB
    float* ml = (float*)((char*)opart + (size_t)33554432);
    float* pstats = ml;                                // 512 floats, consumed before flash
    u16* ob = h;                                      // reuse h after proj0

    gn_wconv_kernel<<<1280, 256, 0, stream>>>(x, wq, wk, wv, wo, pstats, wb);
    hnorm_kernel<<<dim3(64, 16, 2), 256, 0, stream>>>(x, pstats, gw, gb, h);
    proj_kernel<0><<<dim3(64, 12), 256, 0, stream>>>(h, wb, bq, bk, bv, qb, kb, vTb,
                                                     nullptr, nullptr);
    flash_kernel<<<256, 512, 0, stream>>>(qb, kb, vTb, opart, ml);
    merge_kernel<<<2048, 256, 0, stream>>>(opart, ml, ob);
    proj_kernel<1><<<dim3(64, 4), 256, 0, stream>>>(ob, wb + (size_t)3 * 262144, bo, nullptr,
                                                    nullptr, nullptr, nullptr, nullptr, x, out);
}